// Round 2
// baseline (10249.016 us; speedup 1.0000x reference)
//
#include <hip/hip_runtime.h>
#include <math.h>

#define HH 384
#define WW 512
#define HW 196608            // 384*512
#define QHW 49152            // HW/4
#define CHW 983040           // 5*HW
#define NTOT 7864320         // 8*CHW
#define FLOW_N 3145728       // 8*2*HW
#define OUT_FLOW_OFF 16
#define OUT_IMG_OFF (16 + FLOW_N)
#define EPS_F 1e-5f
#define INV_HW (1.0f/196608.0f)

// ---- JAX threefry2x32 (bit-exact integer path), host+device ----
__host__ __device__ __forceinline__ void tf2x32(unsigned k0, unsigned k1,
                                                unsigned x0, unsigned x1,
                                                unsigned& o0, unsigned& o1) {
  const unsigned ks2 = k0 ^ k1 ^ 0x1BD11BDAu;
  x0 += k0; x1 += k1;
#define TFR(r) x0 += x1; x1 = (x1 << (r)) | (x1 >> (32 - (r))); x1 ^= x0;
  TFR(13) TFR(15) TFR(26) TFR(6)
  x0 += k1;  x1 += ks2 + 1u;
  TFR(17) TFR(29) TFR(16) TFR(24)
  x0 += ks2; x1 += k0 + 2u;
  TFR(13) TFR(15) TFR(26) TFR(6)
  x0 += k0;  x1 += k1 + 3u;
  TFR(17) TFR(29) TFR(16) TFR(24)
  x0 += k1;  x1 += ks2 + 4u;
  TFR(13) TFR(15) TFR(26) TFR(6)
  x0 += ks2; x1 += k0 + 5u;
#undef TFR
  o0 = x0; o1 = x1;
}

// bits -> NOISE_STD * sqrt(2) * erfinv(uniform(lo,1))   (JAX normal * 0.05)
__device__ __forceinline__ float noise_from_bits(unsigned bits) {
  const float LO = -0.99999994f;                    // nextafter(-1,0)
  float f = __uint_as_float((bits >> 9) | 0x3F800000u) - 1.0f;  // [0,1)
  float u = fmaxf(LO, f * 2.0f + LO);               // (hi-lo) rounds to 2.0f
  // XLA ErfInv f32 (Giles polynomial)
  float w = -log1pf(-u * u);
  float p;
  if (w < 5.0f) {
    w -= 2.5f;
    p = 2.81022636e-08f;
    p = p * w + 3.43273939e-07f;
    p = p * w + -3.5233877e-06f;
    p = p * w + -4.39150654e-06f;
    p = p * w + 0.00021858087f;
    p = p * w + -0.00125372503f;
    p = p * w + -0.00417768164f;
    p = p * w + 0.246640727f;
    p = p * w + 1.50140941f;
  } else {
    w = sqrtf(w) - 3.0f;
    p = -0.000200214257f;
    p = p * w + 0.000100950558f;
    p = p * w + 0.00134934322f;
    p = p * w + -0.00367342844f;
    p = p * w + 0.00573950773f;
    p = p * w + -0.0076224613f;
    p = p * w + 0.00943887047f;
    p = p * w + 1.00167406f;
    p = p * w + 2.83297682f;
  }
  float z = 1.4142135623730951f * (p * u);
  return 0.05f * z;
}

__device__ __forceinline__ float upd(float x, float g) {
  g = fminf(fmaxf(g, -0.03f), 0.03f);
  return fminf(fmaxf(x - 10.0f * g, -1.0f), 1.0f);
}

// add noise to 4 results and store as float4 (non-final path)
__device__ __forceinline__ void noise_store4(float* dst, const float xn[4],
                                             unsigned ka, unsigned kb, unsigned idx0) {
  float r[4];
#pragma unroll
  for (int j = 0; j < 4; ++j) {
    unsigned o0, o1;
    tf2x32(ka, kb, 0u, idx0 + (unsigned)j, o0, o1);
    r[j] = fminf(fmaxf(xn[j] + noise_from_bits(o0 ^ o1), -1.0f), 1.0f);
  }
  *(float4*)dst = make_float4(r[0], r[1], r[2], r[3]);
}

// ---- kernels ----
__global__ void k_init(double* acc, float* sw, const float* lw) {
  int t = threadIdx.x;
  if (t < 32) acc[t] = 0.0;
  if (t == 32) {
    sw[0] = expf(lw[0]) * INV_HW * 0.5f;    // data-term scale
    sw[1] = expf(lw[1]) * INV_HW * 80.0f;   // smooth-term scale (incl d(flow)/dx = 80)
  }
}

__global__ __launch_bounds__(256) void k_noise0(const float* __restrict__ init,
    float* __restrict__ Y, unsigned ka, unsigned kb) {
  int idx = blockIdx.x * 256 + threadIdx.x;
  unsigned o0, o1;
  tf2x32(ka, kb, 0u, (unsigned)idx, o0, o1);
  float nz = noise_from_bits(o0 ^ o1);
  Y[idx] = fminf(fmaxf(init[idx] + nz, -1.0f), 1.0f);
}

// 4 pixels (along w) per thread
template <bool FINAL>
__global__ __launch_bounds__(256) void k_step4(const float* __restrict__ X,
    float* __restrict__ Y, const float* __restrict__ in2,
    const float* __restrict__ sw, unsigned ka, unsigned kb) {
  int tid = blockIdx.x * 256 + threadIdx.x;   // [0, 8*QHW)
  int b = tid / QHW;
  int q = tid - b * QHW;
  int p = q * 4;                              // pixel base, multiple of 4
  int h = p >> 9, w = p & 511;
  float s0 = sw[0], s1 = sw[1];
  const float* F0 = X + b * CHW;
  const float* F1 = F0 + HW;
  const bool wpos = (w > 0), wend = (w == 508);
  const bool hpos = (h > 0), hlast = (h == 383);

  // ---- flow stencil values (×80); cf[c][4] duplicated at right edge so dx=0 ----
  float cf[2][5], fm1[2], dw[2][4], dwm1[2], uf[2][5];
  {
    float4 a0 = *(const float4*)(F0 + p);
    float4 a1 = *(const float4*)(F1 + p);
    cf[0][0]=80.f*a0.x; cf[0][1]=80.f*a0.y; cf[0][2]=80.f*a0.z; cf[0][3]=80.f*a0.w;
    cf[1][0]=80.f*a1.x; cf[1][1]=80.f*a1.y; cf[1][2]=80.f*a1.z; cf[1][3]=80.f*a1.w;
    cf[0][4] = wend ? cf[0][3] : 80.f * F0[p + 4];
    cf[1][4] = wend ? cf[1][3] : 80.f * F1[p + 4];
    fm1[0] = wpos ? 80.f * F0[p - 1] : cf[0][0];
    fm1[1] = wpos ? 80.f * F1[p - 1] : cf[1][0];
    if (!hlast) {
      float4 d0 = *(const float4*)(F0 + p + WW);
      float4 d1 = *(const float4*)(F1 + p + WW);
      dw[0][0]=80.f*d0.x; dw[0][1]=80.f*d0.y; dw[0][2]=80.f*d0.z; dw[0][3]=80.f*d0.w;
      dw[1][0]=80.f*d1.x; dw[1][1]=80.f*d1.y; dw[1][2]=80.f*d1.z; dw[1][3]=80.f*d1.w;
      dwm1[0] = wpos ? 80.f * F0[p + WW - 1] : fm1[0];
      dwm1[1] = wpos ? 80.f * F1[p + WW - 1] : fm1[1];
    } else {
#pragma unroll
      for (int c = 0; c < 2; ++c) {
        for (int j = 0; j < 4; ++j) dw[c][j] = cf[c][j];   // dy = 0
        dwm1[c] = fm1[c];
      }
    }
    if (hpos) {
      float4 u0 = *(const float4*)(F0 + p - WW);
      float4 u1 = *(const float4*)(F1 + p - WW);
      uf[0][0]=80.f*u0.x; uf[0][1]=80.f*u0.y; uf[0][2]=80.f*u0.z; uf[0][3]=80.f*u0.w;
      uf[1][0]=80.f*u1.x; uf[1][1]=80.f*u1.y; uf[1][2]=80.f*u1.z; uf[1][3]=80.f*u1.w;
      uf[0][4] = wend ? uf[0][3] : 80.f * F0[p - WW + 4];
      uf[1][4] = wend ? uf[1][3] : 80.f * F1[p - WW + 4];
    } else {
#pragma unroll
      for (int c = 0; c < 2; ++c)
        for (int j = 0; j < 5; ++j) uf[c][j] = cf[c][j];   // unused (masked by hpos)
    }
  }

  // ---- shared S sites: SL = S(h,w-1); Sc[j] = S(h,w+j); Su[j] = S(h-1,w+j) ----
  float dxc[2][4], dyc[2][4], invSc[4], dxu[2][4], dyu[2][4], invSu[4];
  float dxl[2], dyl[2], invSL;
#pragma unroll
  for (int j = 0; j < 4; ++j) {
#pragma unroll
    for (int c = 0; c < 2; ++c) {
      dxc[c][j] = cf[c][j + 1] - cf[c][j];
      dyc[c][j] = dw[c][j] - cf[c][j];
      dxu[c][j] = uf[c][j + 1] - uf[c][j];
      dyu[c][j] = cf[c][j] - uf[c][j];
    }
    invSc[j] = 1.0f / sqrtf(dxc[0][j]*dxc[0][j] + dxc[1][j]*dxc[1][j]
                          + dyc[0][j]*dyc[0][j] + dyc[1][j]*dyc[1][j] + EPS_F);
    invSu[j] = 1.0f / sqrtf(dxu[0][j]*dxu[0][j] + dxu[1][j]*dxu[1][j]
                          + dyu[0][j]*dyu[0][j] + dyu[1][j]*dyu[1][j] + EPS_F);
  }
  dxl[0] = cf[0][0] - fm1[0];  dxl[1] = cf[1][0] - fm1[1];
  dyl[0] = dwm1[0] - fm1[0];   dyl[1] = dwm1[1] - fm1[1];
  invSL = 1.0f / sqrtf(dxl[0]*dxl[0] + dxl[1]*dxl[1]
                     + dyl[0]*dyl[0] + dyl[1]*dyl[1] + EPS_F);

  // ---- flow grads + update ----
  float xnF[2][4];
#pragma unroll
  for (int j = 0; j < 4; ++j) {
#pragma unroll
    for (int c = 0; c < 2; ++c) {
      float g = -(dxc[c][j] + dyc[c][j]) * invSc[j];
      if (j == 0) { if (wpos) g += dxl[c] * invSL; }
      else        { g += dxc[c][j - 1] * invSc[j - 1]; }
      if (hpos)   { g += dyu[c][j] * invSu[j]; }
      xnF[c][j] = upd(cf[c][j] * (1.0f/80.0f), g * s1);
    }
  }

  // ---- img channels (pixel-local data term) ----
  const float* XI = F0 + 2 * HW;
  const float* I2 = in2 + b * 3 * HW;
  float xv[3][4], dI[3][4];
#pragma unroll
  for (int c = 0; c < 3; ++c) {
    float4 xvv = *(const float4*)(XI + c * HW + p);
    float4 ivv = *(const float4*)(I2 + c * HW + p);
    float xa[4] = {xvv.x, xvv.y, xvv.z, xvv.w};
    float ia[4] = {ivv.x, ivv.y, ivv.z, ivv.w};
#pragma unroll
    for (int j = 0; j < 4; ++j) {
      xv[c][j] = xa[j];
      dI[c][j] = (xa[j] + 1.0f) * 0.5f - ((ia[j] * 2.0f - 1.0f) + 1.0f) * 0.5f;
    }
  }
  float xnI[3][4];
#pragma unroll
  for (int j = 0; j < 4; ++j) {
    float A = dI[0][j]*dI[0][j] + dI[1][j]*dI[1][j] + dI[2][j]*dI[2][j];
    float sI = s0 / sqrtf(A + EPS_F);
#pragma unroll
    for (int c = 0; c < 3; ++c) xnI[c][j] = upd(xv[c][j], dI[c][j] * sI);
  }

  // ---- noise + store (or final transform) ----
  if (!FINAL) {
    int base = b * CHW + p;
    noise_store4(Y + base,          xnF[0], ka, kb, (unsigned)base);
    noise_store4(Y + base + HW,     xnF[1], ka, kb, (unsigned)(base + HW));
#pragma unroll
    for (int c = 0; c < 3; ++c)
      noise_store4(Y + base + (2 + c) * HW, xnI[c], ka, kb,
                   (unsigned)(base + (2 + c) * HW));
  } else {
    float* outF = Y + OUT_FLOW_OFF + b * 2 * HW;
    *(float4*)(outF + p)      = make_float4(xnF[0][0]*80.f, xnF[0][1]*80.f,
                                            xnF[0][2]*80.f, xnF[0][3]*80.f);
    *(float4*)(outF + HW + p) = make_float4(xnF[1][0]*80.f, xnF[1][1]*80.f,
                                            xnF[1][2]*80.f, xnF[1][3]*80.f);
    float* outI = Y + OUT_IMG_OFF + b * 3 * HW;
#pragma unroll
    for (int c = 0; c < 3; ++c)
      *(float4*)(outI + c * HW + p) = make_float4((xnI[c][0]+1.f)*0.5f,
                                                  (xnI[c][1]+1.f)*0.5f,
                                                  (xnI[c][2]+1.f)*0.5f,
                                                  (xnI[c][3]+1.f)*0.5f);
  }
}

__device__ __forceinline__ void block_acc2(double v0, double v1, double* a0, double* a1) {
  for (int off = 32; off > 0; off >>= 1) {
    v0 += __shfl_down(v0, off, 64);
    v1 += __shfl_down(v1, off, 64);
  }
  __shared__ double s0m[4], s1m[4];
  int lane = threadIdx.x & 63, wv = threadIdx.x >> 6;
  if (lane == 0) { s0m[wv] = v0; s1m[wv] = v1; }
  __syncthreads();
  if (threadIdx.x == 0) {
    atomicAdd(a0, s0m[0] + s0m[1] + s0m[2] + s0m[3]);
    atomicAdd(a1, s1m[0] + s1m[1] + s1m[2] + s1m[3]);
  }
}

// 96 blocks per batch, each covering 8 contiguous 256-px chunks
__global__ __launch_bounds__(256) void k_pos_energy(const float* __restrict__ t1,
    const float* __restrict__ in1, const float* __restrict__ in2,
    double* __restrict__ acc) {
  int blk = blockIdx.x;
  int b = blk / 96;
  int local = blk - b * 96;
  const float* T0 = t1 + b * 2 * HW;
  const float* T1 = T0 + HW;
  const float* I1 = in1 + b * 3 * HW;
  const float* I2 = in2 + b * 3 * HW;
  double data = 0.0, smooth = 0.0;
  for (int it = 0; it < 8; ++it) {
    int p = (local * 8 + it) * 256 + threadIdx.x;
    int h = p >> 9, w = p & 511;
    float f00 = (T0[p] / 80.0f) * 80.0f;     // mirror (t/80)*80 roundtrip
    float f10 = (T1[p] / 80.0f) * 80.0f;
    float dx0 = 0, dx1 = 0, dy0 = 0, dy1 = 0;
    if (w < 511) { dx0 = (T0[p+1]/80.0f)*80.0f - f00;  dx1 = (T1[p+1]/80.0f)*80.0f - f10; }
    if (h < 383) { dy0 = (T0[p+WW]/80.0f)*80.0f - f00; dy1 = (T1[p+WW]/80.0f)*80.0f - f10; }
    smooth += (double)sqrtf(dx0*dx0 + dx1*dx1 + dy0*dy0 + dy1*dy1 + EPS_F);
    float d0 = ((I1[p]*2.0f-1.0f)+1.0f)*0.5f        - ((I2[p]*2.0f-1.0f)+1.0f)*0.5f;
    float d1 = ((I1[p+HW]*2.0f-1.0f)+1.0f)*0.5f     - ((I2[p+HW]*2.0f-1.0f)+1.0f)*0.5f;
    float d2 = ((I1[p+2*HW]*2.0f-1.0f)+1.0f)*0.5f   - ((I2[p+2*HW]*2.0f-1.0f)+1.0f)*0.5f;
    data += (double)sqrtf(d0*d0 + d1*d1 + d2*d2 + EPS_F);
  }
  block_acc2(data, smooth, &acc[b], &acc[8 + b]);
}

__global__ __launch_bounds__(256) void k_neg_energy(const float* __restrict__ out,
    const float* __restrict__ in2, double* __restrict__ acc) {
  int blk = blockIdx.x;
  int b = blk / 96;
  int local = blk - b * 96;
  const float* F0 = out + OUT_FLOW_OFF + b * 2 * HW;   // already = 80*x
  const float* F1 = F0 + HW;
  const float* I = out + OUT_IMG_OFF + b * 3 * HW;     // already = (x+1)/2
  const float* I2 = in2 + b * 3 * HW;
  double data = 0.0, smooth = 0.0;
  for (int it = 0; it < 8; ++it) {
    int p = (local * 8 + it) * 256 + threadIdx.x;
    int h = p >> 9, w = p & 511;
    float f00 = F0[p], f10 = F1[p];
    float dx0 = 0, dx1 = 0, dy0 = 0, dy1 = 0;
    if (w < 511) { dx0 = F0[p + 1] - f00;  dx1 = F1[p + 1] - f10; }
    if (h < 383) { dy0 = F0[p + WW] - f00; dy1 = F1[p + WW] - f10; }
    smooth += (double)sqrtf(dx0*dx0 + dx1*dx1 + dy0*dy0 + dy1*dy1 + EPS_F);
    float d0 = I[p]        - ((I2[p]*2.0f-1.0f)+1.0f)*0.5f;
    float d1 = I[p+HW]     - ((I2[p+HW]*2.0f-1.0f)+1.0f)*0.5f;
    float d2 = I[p+2*HW]   - ((I2[p+2*HW]*2.0f-1.0f)+1.0f)*0.5f;
    data += (double)sqrtf(d0*d0 + d1*d1 + d2*d2 + EPS_F);
  }
  block_acc2(data, smooth, &acc[16 + b], &acc[24 + b]);
}

__global__ void k_finalize(const double* __restrict__ acc,
                           const float* __restrict__ lw, float* __restrict__ out) {
  int t = threadIdx.x;
  if (t < 16) {
    int b = t & 7, neg = t >> 3;
    double data   = acc[neg * 16 + b];
    double smooth = acc[neg * 16 + 8 + b];
    double e0 = exp((double)lw[0]), e1 = exp((double)lw[1]);
    out[t] = (float)((e0 * data + e1 * smooth) / 196608.0);
  }
}

extern "C" void kernel_launch(void* const* d_in, const int* in_sizes, int n_in,
                              void* d_out, int out_size, void* d_ws, size_t ws_size,
                              hipStream_t stream) {
  const float* t1  = (const float*)d_in[0];
  const float* in1 = (const float*)d_in[1];
  const float* in2 = (const float*)d_in[2];
  const float* init = (const float*)d_in[3];
  const float* lw  = (const float*)d_in[4];
  float* out = (float*)d_out;

  double* acc = (double*)d_ws;                          // 32 doubles
  float* sw = (float*)((char*)d_ws + 256);              // 2 floats
  size_t need = 2048 + (size_t)NTOT * sizeof(float);
  float* bufA = (ws_size >= need) ? (float*)((char*)d_ws + 2048)
                                  : (float*)d_in[3];    // fallback: reuse init
  float* bufE = out + OUT_FLOW_OFF;                     // even-t states live in d_out

  // host-side threefry split: keys[t] = tf(0,1,0,t)  (pure integer function)
  unsigned K0[200], K1[200];
  for (int t = 0; t < 200; ++t) tf2x32(0u, 1u, 0u, (unsigned)t, K0[t], K1[t]);

  k_init<<<1, 64, 0, stream>>>(acc, sw, lw);
  k_pos_energy<<<8 * 96, 256, 0, stream>>>(t1, in1, in2, acc);
  k_noise0<<<NTOT / 256, 256, 0, stream>>>(init, bufE, K0[0], K1[0]);   // n_0 (even)
  for (int t = 0; t < 199; ++t) {
    const float* src = (t % 2 == 0) ? bufE : bufA;
    float* dst       = (t % 2 == 0) ? bufA : bufE;
    k_step4<false><<<8 * QHW / 256, 256, 0, stream>>>(src, dst, in2, sw,
                                                      K0[t + 1], K1[t + 1]);
  }
  // n_199 is in bufA (odd); final grad step writes transformed outputs
  k_step4<true><<<8 * QHW / 256, 256, 0, stream>>>(bufA, out, in2, sw, 0u, 0u);
  k_neg_energy<<<8 * 96, 256, 0, stream>>>(out, in2, acc);
  k_finalize<<<1, 64, 0, stream>>>(acc, lw, out);
}

// Round 3
// 5602.431 us; speedup vs baseline: 1.8294x; 1.8294x over previous
//
#include <hip/hip_runtime.h>
#include <math.h>

#define HH 384
#define WW 512
#define HW 196608            // 384*512
#define QHW 49152            // HW/4
#define CHW 983040           // 5*HW
#define NTOT 7864320         // 8*CHW
#define FLOW_N 3145728       // 8*2*HW
#define OUT_FLOW_OFF 16
#define OUT_IMG_OFF (16 + FLOW_N)
#define EPS_F 1e-5f
#define INV_HW (1.0f/196608.0f)

// single-instruction HW transcendentals (v_rsq_f32 / v_log_f32 / v_sqrt_f32, ~1 ulp)
__device__ __forceinline__ float rsq_f(float x)  { return __builtin_amdgcn_rsqf(x); }
__device__ __forceinline__ float ln_f(float x)   { return 0.69314718055994531f * __builtin_amdgcn_logf(x); }
__device__ __forceinline__ float sqrt_f(float x) { return __builtin_amdgcn_sqrtf(x); }

// ---- JAX threefry2x32 (bit-exact integer path), host+device ----
__host__ __device__ __forceinline__ void tf2x32(unsigned k0, unsigned k1,
                                                unsigned x0, unsigned x1,
                                                unsigned& o0, unsigned& o1) {
  const unsigned ks2 = k0 ^ k1 ^ 0x1BD11BDAu;
  x0 += k0; x1 += k1;
#define TFR(r) x0 += x1; x1 = (x1 << (r)) | (x1 >> (32 - (r))); x1 ^= x0;
  TFR(13) TFR(15) TFR(26) TFR(6)
  x0 += k1;  x1 += ks2 + 1u;
  TFR(17) TFR(29) TFR(16) TFR(24)
  x0 += ks2; x1 += k0 + 2u;
  TFR(13) TFR(15) TFR(26) TFR(6)
  x0 += k0;  x1 += k1 + 3u;
  TFR(17) TFR(29) TFR(16) TFR(24)
  x0 += k1;  x1 += ks2 + 4u;
  TFR(13) TFR(15) TFR(26) TFR(6)
  x0 += ks2; x1 += k0 + 5u;
#undef TFR
  o0 = x0; o1 = x1;
}

// bits -> NOISE_STD * sqrt(2) * erfinv(uniform(lo,1))   (JAX normal * 0.05)
__device__ __forceinline__ float noise_from_bits(unsigned bits) {
  const float LO = -0.99999994f;                    // nextafter(-1,0)
  float f = __uint_as_float((bits >> 9) | 0x3F800000u) - 1.0f;  // [0,1)
  float u = fmaxf(LO, f * 2.0f + LO);               // (hi-lo) rounds to 2.0f
  // -log1p(-u^2) via factored form (accurate near |u|~1) + HW log
  float w = -ln_f((1.0f - u) * (1.0f + u));
  float p;
  if (w < 5.0f) {
    w -= 2.5f;
    p = 2.81022636e-08f;
    p = p * w + 3.43273939e-07f;
    p = p * w + -3.5233877e-06f;
    p = p * w + -4.39150654e-06f;
    p = p * w + 0.00021858087f;
    p = p * w + -0.00125372503f;
    p = p * w + -0.00417768164f;
    p = p * w + 0.246640727f;
    p = p * w + 1.50140941f;
  } else {
    w = sqrt_f(w) - 3.0f;
    p = -0.000200214257f;
    p = p * w + 0.000100950558f;
    p = p * w + 0.00134934322f;
    p = p * w + -0.00367342844f;
    p = p * w + 0.00573950773f;
    p = p * w + -0.0076224613f;
    p = p * w + 0.00943887047f;
    p = p * w + 1.00167406f;
    p = p * w + 2.83297682f;
  }
  float z = 1.4142135623730951f * (p * u);
  return 0.05f * z;
}

__device__ __forceinline__ float upd(float x, float g) {
  g = fminf(fmaxf(g, -0.03f), 0.03f);
  return fminf(fmaxf(x - 10.0f * g, -1.0f), 1.0f);
}

// add noise to 4 results and store as float4 (non-final path)
__device__ __forceinline__ void noise_store4(float* dst, const float xn[4],
                                             unsigned ka, unsigned kb, unsigned idx0) {
  float r[4];
#pragma unroll
  for (int j = 0; j < 4; ++j) {
    unsigned o0, o1;
    tf2x32(ka, kb, 0u, idx0 + (unsigned)j, o0, o1);
    r[j] = fminf(fmaxf(xn[j] + noise_from_bits(o0 ^ o1), -1.0f), 1.0f);
  }
  *(float4*)dst = make_float4(r[0], r[1], r[2], r[3]);
}

// ---- kernels ----
__global__ void k_init(double* acc, float* sw, const float* lw) {
  int t = threadIdx.x;
  if (t < 32) acc[t] = 0.0;
  if (t == 32) {
    sw[0] = expf(lw[0]) * INV_HW * 0.5f;    // data-term scale
    sw[1] = expf(lw[1]) * INV_HW * 80.0f;   // smooth-term scale (incl d(flow)/dx = 80)
  }
}

__global__ __launch_bounds__(256) void k_noise0(const float* __restrict__ init,
    float* __restrict__ Y, unsigned ka, unsigned kb) {
  int idx = blockIdx.x * 256 + threadIdx.x;
  unsigned o0, o1;
  tf2x32(ka, kb, 0u, (unsigned)idx, o0, o1);
  float nz = noise_from_bits(o0 ^ o1);
  Y[idx] = fminf(fmaxf(init[idx] + nz, -1.0f), 1.0f);
}

// 4 pixels (along w) per thread
template <bool FINAL>
__global__ __launch_bounds__(256) void k_step4(const float* __restrict__ X,
    float* __restrict__ Y, const float* __restrict__ in2,
    const float* __restrict__ sw, unsigned ka, unsigned kb) {
  int tid = blockIdx.x * 256 + threadIdx.x;   // [0, 8*QHW)
  int b = tid / QHW;
  int q = tid - b * QHW;
  int p = q * 4;                              // pixel base, multiple of 4
  int h = p >> 9, w = p & 511;
  float s0 = sw[0], s1 = sw[1];
  const float* F0 = X + b * CHW;
  const float* F1 = F0 + HW;
  const bool wpos = (w > 0), wend = (w == 508);
  const bool hpos = (h > 0), hlast = (h == 383);

  // ---- flow stencil values (×80); cf[c][4] duplicated at right edge so dx=0 ----
  float cf[2][5], fm1[2], dw[2][4], dwm1[2], uf[2][5];
  {
    float4 a0 = *(const float4*)(F0 + p);
    float4 a1 = *(const float4*)(F1 + p);
    cf[0][0]=80.f*a0.x; cf[0][1]=80.f*a0.y; cf[0][2]=80.f*a0.z; cf[0][3]=80.f*a0.w;
    cf[1][0]=80.f*a1.x; cf[1][1]=80.f*a1.y; cf[1][2]=80.f*a1.z; cf[1][3]=80.f*a1.w;
    cf[0][4] = wend ? cf[0][3] : 80.f * F0[p + 4];
    cf[1][4] = wend ? cf[1][3] : 80.f * F1[p + 4];
    fm1[0] = wpos ? 80.f * F0[p - 1] : cf[0][0];
    fm1[1] = wpos ? 80.f * F1[p - 1] : cf[1][0];
    if (!hlast) {
      float4 d0 = *(const float4*)(F0 + p + WW);
      float4 d1 = *(const float4*)(F1 + p + WW);
      dw[0][0]=80.f*d0.x; dw[0][1]=80.f*d0.y; dw[0][2]=80.f*d0.z; dw[0][3]=80.f*d0.w;
      dw[1][0]=80.f*d1.x; dw[1][1]=80.f*d1.y; dw[1][2]=80.f*d1.z; dw[1][3]=80.f*d1.w;
      dwm1[0] = wpos ? 80.f * F0[p + WW - 1] : fm1[0];
      dwm1[1] = wpos ? 80.f * F1[p + WW - 1] : fm1[1];
    } else {
#pragma unroll
      for (int c = 0; c < 2; ++c) {
        for (int j = 0; j < 4; ++j) dw[c][j] = cf[c][j];   // dy = 0
        dwm1[c] = fm1[c];
      }
    }
    if (hpos) {
      float4 u0 = *(const float4*)(F0 + p - WW);
      float4 u1 = *(const float4*)(F1 + p - WW);
      uf[0][0]=80.f*u0.x; uf[0][1]=80.f*u0.y; uf[0][2]=80.f*u0.z; uf[0][3]=80.f*u0.w;
      uf[1][0]=80.f*u1.x; uf[1][1]=80.f*u1.y; uf[1][2]=80.f*u1.z; uf[1][3]=80.f*u1.w;
      uf[0][4] = wend ? uf[0][3] : 80.f * F0[p - WW + 4];
      uf[1][4] = wend ? uf[1][3] : 80.f * F1[p - WW + 4];
    } else {
#pragma unroll
      for (int c = 0; c < 2; ++c)
        for (int j = 0; j < 5; ++j) uf[c][j] = cf[c][j];   // unused (masked by hpos)
    }
  }

  // ---- shared S sites: SL = S(h,w-1); Sc[j] = S(h,w+j); Su[j] = S(h-1,w+j) ----
  float dxc[2][4], dyc[2][4], invSc[4], dxu[2][4], dyu[2][4], invSu[4];
  float dxl[2], dyl[2], invSL;
#pragma unroll
  for (int j = 0; j < 4; ++j) {
#pragma unroll
    for (int c = 0; c < 2; ++c) {
      dxc[c][j] = cf[c][j + 1] - cf[c][j];
      dyc[c][j] = dw[c][j] - cf[c][j];
      dxu[c][j] = uf[c][j + 1] - uf[c][j];
      dyu[c][j] = cf[c][j] - uf[c][j];
    }
    invSc[j] = rsq_f(dxc[0][j]*dxc[0][j] + dxc[1][j]*dxc[1][j]
                   + dyc[0][j]*dyc[0][j] + dyc[1][j]*dyc[1][j] + EPS_F);
    invSu[j] = rsq_f(dxu[0][j]*dxu[0][j] + dxu[1][j]*dxu[1][j]
                   + dyu[0][j]*dyu[0][j] + dyu[1][j]*dyu[1][j] + EPS_F);
  }
  dxl[0] = cf[0][0] - fm1[0];  dxl[1] = cf[1][0] - fm1[1];
  dyl[0] = dwm1[0] - fm1[0];   dyl[1] = dwm1[1] - fm1[1];
  invSL = rsq_f(dxl[0]*dxl[0] + dxl[1]*dxl[1]
              + dyl[0]*dyl[0] + dyl[1]*dyl[1] + EPS_F);

  // ---- flow grads + update ----
  float xnF[2][4];
#pragma unroll
  for (int j = 0; j < 4; ++j) {
#pragma unroll
    for (int c = 0; c < 2; ++c) {
      float g = -(dxc[c][j] + dyc[c][j]) * invSc[j];
      if (j == 0) { if (wpos) g += dxl[c] * invSL; }
      else        { g += dxc[c][j - 1] * invSc[j - 1]; }
      if (hpos)   { g += dyu[c][j] * invSu[j]; }
      xnF[c][j] = upd(cf[c][j] * (1.0f/80.0f), g * s1);
    }
  }

  // ---- img channels (pixel-local data term) ----
  const float* XI = F0 + 2 * HW;
  const float* I2 = in2 + b * 3 * HW;
  float xv[3][4], dI[3][4];
#pragma unroll
  for (int c = 0; c < 3; ++c) {
    float4 xvv = *(const float4*)(XI + c * HW + p);
    float4 ivv = *(const float4*)(I2 + c * HW + p);
    float xa[4] = {xvv.x, xvv.y, xvv.z, xvv.w};
    float ia[4] = {ivv.x, ivv.y, ivv.z, ivv.w};
#pragma unroll
    for (int j = 0; j < 4; ++j) {
      xv[c][j] = xa[j];
      dI[c][j] = (xa[j] + 1.0f) * 0.5f - ((ia[j] * 2.0f - 1.0f) + 1.0f) * 0.5f;
    }
  }
  float xnI[3][4];
#pragma unroll
  for (int j = 0; j < 4; ++j) {
    float A = dI[0][j]*dI[0][j] + dI[1][j]*dI[1][j] + dI[2][j]*dI[2][j];
    float sI = s0 * rsq_f(A + EPS_F);
#pragma unroll
    for (int c = 0; c < 3; ++c) xnI[c][j] = upd(xv[c][j], dI[c][j] * sI);
  }

  // ---- noise + store (or final transform) ----
  if (!FINAL) {
    int base = b * CHW + p;
    noise_store4(Y + base,          xnF[0], ka, kb, (unsigned)base);
    noise_store4(Y + base + HW,     xnF[1], ka, kb, (unsigned)(base + HW));
#pragma unroll
    for (int c = 0; c < 3; ++c)
      noise_store4(Y + base + (2 + c) * HW, xnI[c], ka, kb,
                   (unsigned)(base + (2 + c) * HW));
  } else {
    float* outF = Y + OUT_FLOW_OFF + b * 2 * HW;
    *(float4*)(outF + p)      = make_float4(xnF[0][0]*80.f, xnF[0][1]*80.f,
                                            xnF[0][2]*80.f, xnF[0][3]*80.f);
    *(float4*)(outF + HW + p) = make_float4(xnF[1][0]*80.f, xnF[1][1]*80.f,
                                            xnF[1][2]*80.f, xnF[1][3]*80.f);
    float* outI = Y + OUT_IMG_OFF + b * 3 * HW;
#pragma unroll
    for (int c = 0; c < 3; ++c)
      *(float4*)(outI + c * HW + p) = make_float4((xnI[c][0]+1.f)*0.5f,
                                                  (xnI[c][1]+1.f)*0.5f,
                                                  (xnI[c][2]+1.f)*0.5f,
                                                  (xnI[c][3]+1.f)*0.5f);
  }
}

__device__ __forceinline__ void block_acc2(double v0, double v1, double* a0, double* a1) {
  for (int off = 32; off > 0; off >>= 1) {
    v0 += __shfl_down(v0, off, 64);
    v1 += __shfl_down(v1, off, 64);
  }
  __shared__ double s0m[4], s1m[4];
  int lane = threadIdx.x & 63, wv = threadIdx.x >> 6;
  if (lane == 0) { s0m[wv] = v0; s1m[wv] = v1; }
  __syncthreads();
  if (threadIdx.x == 0) {
    atomicAdd(a0, s0m[0] + s0m[1] + s0m[2] + s0m[3]);
    atomicAdd(a1, s1m[0] + s1m[1] + s1m[2] + s1m[3]);
  }
}

// 96 blocks per batch, each covering 8 contiguous 256-px chunks
__global__ __launch_bounds__(256) void k_pos_energy(const float* __restrict__ t1,
    const float* __restrict__ in1, const float* __restrict__ in2,
    double* __restrict__ acc) {
  int blk = blockIdx.x;
  int b = blk / 96;
  int local = blk - b * 96;
  const float* T0 = t1 + b * 2 * HW;
  const float* T1 = T0 + HW;
  const float* I1 = in1 + b * 3 * HW;
  const float* I2 = in2 + b * 3 * HW;
  double data = 0.0, smooth = 0.0;
  for (int it = 0; it < 8; ++it) {
    int p = (local * 8 + it) * 256 + threadIdx.x;
    int h = p >> 9, w = p & 511;
    float f00 = (T0[p] / 80.0f) * 80.0f;     // mirror (t/80)*80 roundtrip
    float f10 = (T1[p] / 80.0f) * 80.0f;
    float dx0 = 0, dx1 = 0, dy0 = 0, dy1 = 0;
    if (w < 511) { dx0 = (T0[p+1]/80.0f)*80.0f - f00;  dx1 = (T1[p+1]/80.0f)*80.0f - f10; }
    if (h < 383) { dy0 = (T0[p+WW]/80.0f)*80.0f - f00; dy1 = (T1[p+WW]/80.0f)*80.0f - f10; }
    smooth += (double)sqrtf(dx0*dx0 + dx1*dx1 + dy0*dy0 + dy1*dy1 + EPS_F);
    float d0 = ((I1[p]*2.0f-1.0f)+1.0f)*0.5f        - ((I2[p]*2.0f-1.0f)+1.0f)*0.5f;
    float d1 = ((I1[p+HW]*2.0f-1.0f)+1.0f)*0.5f     - ((I2[p+HW]*2.0f-1.0f)+1.0f)*0.5f;
    float d2 = ((I1[p+2*HW]*2.0f-1.0f)+1.0f)*0.5f   - ((I2[p+2*HW]*2.0f-1.0f)+1.0f)*0.5f;
    data += (double)sqrtf(d0*d0 + d1*d1 + d2*d2 + EPS_F);
  }
  block_acc2(data, smooth, &acc[b], &acc[8 + b]);
}

__global__ __launch_bounds__(256) void k_neg_energy(const float* __restrict__ out,
    const float* __restrict__ in2, double* __restrict__ acc) {
  int blk = blockIdx.x;
  int b = blk / 96;
  int local = blk - b * 96;
  const float* F0 = out + OUT_FLOW_OFF + b * 2 * HW;   // already = 80*x
  const float* F1 = F0 + HW;
  const float* I = out + OUT_IMG_OFF + b * 3 * HW;     // already = (x+1)/2
  const float* I2 = in2 + b * 3 * HW;
  double data = 0.0, smooth = 0.0;
  for (int it = 0; it < 8; ++it) {
    int p = (local * 8 + it) * 256 + threadIdx.x;
    int h = p >> 9, w = p & 511;
    float f00 = F0[p], f10 = F1[p];
    float dx0 = 0, dx1 = 0, dy0 = 0, dy1 = 0;
    if (w < 511) { dx0 = F0[p + 1] - f00;  dx1 = F1[p + 1] - f10; }
    if (h < 383) { dy0 = F0[p + WW] - f00; dy1 = F1[p + WW] - f10; }
    smooth += (double)sqrtf(dx0*dx0 + dx1*dx1 + dy0*dy0 + dy1*dy1 + EPS_F);
    float d0 = I[p]        - ((I2[p]*2.0f-1.0f)+1.0f)*0.5f;
    float d1 = I[p+HW]     - ((I2[p+HW]*2.0f-1.0f)+1.0f)*0.5f;
    float d2 = I[p+2*HW]   - ((I2[p+2*HW]*2.0f-1.0f)+1.0f)*0.5f;
    data += (double)sqrtf(d0*d0 + d1*d1 + d2*d2 + EPS_F);
  }
  block_acc2(data, smooth, &acc[16 + b], &acc[24 + b]);
}

__global__ void k_finalize(const double* __restrict__ acc,
                           const float* __restrict__ lw, float* __restrict__ out) {
  int t = threadIdx.x;
  if (t < 16) {
    int b = t & 7, neg = t >> 3;
    double data   = acc[neg * 16 + b];
    double smooth = acc[neg * 16 + 8 + b];
    double e0 = exp((double)lw[0]), e1 = exp((double)lw[1]);
    out[t] = (float)((e0 * data + e1 * smooth) / 196608.0);
  }
}

extern "C" void kernel_launch(void* const* d_in, const int* in_sizes, int n_in,
                              void* d_out, int out_size, void* d_ws, size_t ws_size,
                              hipStream_t stream) {
  const float* t1  = (const float*)d_in[0];
  const float* in1 = (const float*)d_in[1];
  const float* in2 = (const float*)d_in[2];
  const float* init = (const float*)d_in[3];
  const float* lw  = (const float*)d_in[4];
  float* out = (float*)d_out;

  double* acc = (double*)d_ws;                          // 32 doubles
  float* sw = (float*)((char*)d_ws + 256);              // 2 floats
  size_t need = 2048 + (size_t)NTOT * sizeof(float);
  float* bufA = (ws_size >= need) ? (float*)((char*)d_ws + 2048)
                                  : (float*)d_in[3];    // fallback: reuse init
  float* bufE = out + OUT_FLOW_OFF;                     // even-t states live in d_out

  // host-side threefry split: keys[t] = tf(0,1,0,t)  (pure integer function)
  unsigned K0[200], K1[200];
  for (int t = 0; t < 200; ++t) tf2x32(0u, 1u, 0u, (unsigned)t, K0[t], K1[t]);

  k_init<<<1, 64, 0, stream>>>(acc, sw, lw);
  k_pos_energy<<<8 * 96, 256, 0, stream>>>(t1, in1, in2, acc);
  k_noise0<<<NTOT / 256, 256, 0, stream>>>(init, bufE, K0[0], K1[0]);   // n_0 (even)
  for (int t = 0; t < 199; ++t) {
    const float* src = (t % 2 == 0) ? bufE : bufA;
    float* dst       = (t % 2 == 0) ? bufA : bufE;
    k_step4<false><<<8 * QHW / 256, 256, 0, stream>>>(src, dst, in2, sw,
                                                      K0[t + 1], K1[t + 1]);
  }
  // n_199 is in bufA (odd); final grad step writes transformed outputs
  k_step4<true><<<8 * QHW / 256, 256, 0, stream>>>(bufA, out, in2, sw, 0u, 0u);
  k_neg_energy<<<8 * 96, 256, 0, stream>>>(out, in2, acc);
  k_finalize<<<1, 64, 0, stream>>>(acc, lw, out);
}

// Round 4
// 5518.682 us; speedup vs baseline: 1.8571x; 1.0152x over previous
//
#include <hip/hip_runtime.h>
#include <math.h>

#define HH 384
#define WW 512
#define HW 196608            // 384*512
#define HHW 98304            // HW/2
#define CHW 983040           // 5*HW
#define NTOT 7864320         // 8*CHW
#define FLOW_N 3145728       // 8*2*HW
#define OUT_FLOW_OFF 16
#define OUT_IMG_OFF (16 + FLOW_N)
#define EPS_F 1e-5f
#define EPS_S (1e-5f / 6400.0f)   // smooth-term eps in raw-x domain (S is deg-1 homog in 80x)
#define INV_HW (1.0f/196608.0f)

// single-instruction HW transcendentals (v_rsq_f32 / v_log_f32 / v_sqrt_f32, ~1 ulp)
__device__ __forceinline__ float rsq_f(float x)  { return __builtin_amdgcn_rsqf(x); }
__device__ __forceinline__ float ln_f(float x)   { return 0.69314718055994531f * __builtin_amdgcn_logf(x); }
__device__ __forceinline__ float sqrt_f(float x) { return __builtin_amdgcn_sqrtf(x); }

// ---- JAX threefry2x32 (bit-exact integer path), host+device ----
__host__ __device__ __forceinline__ void tf2x32(unsigned k0, unsigned k1,
                                                unsigned x0, unsigned x1,
                                                unsigned& o0, unsigned& o1) {
  const unsigned ks2 = k0 ^ k1 ^ 0x1BD11BDAu;
  x0 += k0; x1 += k1;
#define TFR(r) x0 += x1; x1 = (x1 << (r)) | (x1 >> (32 - (r))); x1 ^= x0;
  TFR(13) TFR(15) TFR(26) TFR(6)
  x0 += k1;  x1 += ks2 + 1u;
  TFR(17) TFR(29) TFR(16) TFR(24)
  x0 += ks2; x1 += k0 + 2u;
  TFR(13) TFR(15) TFR(26) TFR(6)
  x0 += k0;  x1 += k1 + 3u;
  TFR(17) TFR(29) TFR(16) TFR(24)
  x0 += k1;  x1 += ks2 + 4u;
  TFR(13) TFR(15) TFR(26) TFR(6)
  x0 += ks2; x1 += k0 + 5u;
#undef TFR
  o0 = x0; o1 = x1;
}

// bits -> NOISE_STD * sqrt(2) * erfinv(uniform(lo,1))   (JAX normal * 0.05)
__device__ __forceinline__ float noise_from_bits(unsigned bits) {
  const float LO = -0.99999994f;                    // nextafter(-1,0)
  float f = __uint_as_float((bits >> 9) | 0x3F800000u) - 1.0f;  // [0,1)
  float u = fmaxf(LO, f * 2.0f + LO);               // (hi-lo) rounds to 2.0f
  // -log1p(-u^2) via factored form (accurate near |u|~1) + HW log
  float w = -ln_f((1.0f - u) * (1.0f + u));
  float p;
  if (w < 5.0f) {
    w -= 2.5f;
    p = 2.81022636e-08f;
    p = p * w + 3.43273939e-07f;
    p = p * w + -3.5233877e-06f;
    p = p * w + -4.39150654e-06f;
    p = p * w + 0.00021858087f;
    p = p * w + -0.00125372503f;
    p = p * w + -0.00417768164f;
    p = p * w + 0.246640727f;
    p = p * w + 1.50140941f;
  } else {
    w = sqrt_f(w) - 3.0f;
    p = -0.000200214257f;
    p = p * w + 0.000100950558f;
    p = p * w + 0.00134934322f;
    p = p * w + -0.00367342844f;
    p = p * w + 0.00573950773f;
    p = p * w + -0.0076224613f;
    p = p * w + 0.00943887047f;
    p = p * w + 1.00167406f;
    p = p * w + 2.83297682f;
  }
  float z = 1.4142135623730951f * (p * u);
  return 0.05f * z;
}

__device__ __forceinline__ float upd(float x, float g) {
  g = fminf(fmaxf(g, -0.03f), 0.03f);
  return fminf(fmaxf(x - 10.0f * g, -1.0f), 1.0f);
}

// add noise to 2 results and store as float2 (non-final path)
__device__ __forceinline__ void noise_store2(float* dst, const float xn[2],
                                             unsigned ka, unsigned kb, unsigned idx0) {
  unsigned o0, o1, o2, o3;
  tf2x32(ka, kb, 0u, idx0, o0, o1);
  tf2x32(ka, kb, 0u, idx0 + 1u, o2, o3);
  float r0 = fminf(fmaxf(xn[0] + noise_from_bits(o0 ^ o1), -1.0f), 1.0f);
  float r1 = fminf(fmaxf(xn[1] + noise_from_bits(o2 ^ o3), -1.0f), 1.0f);
  *(float2*)dst = make_float2(r0, r1);
}

// ---- kernels ----
__global__ void k_init(double* acc, float* sw, const float* lw) {
  int t = threadIdx.x;
  if (t < 32) acc[t] = 0.0;
  if (t == 32) {
    sw[0] = expf(lw[0]) * INV_HW * 0.5f;    // data-term scale
    sw[1] = expf(lw[1]) * INV_HW * 80.0f;   // smooth-term scale (incl d(flow)/dx = 80)
  }
}

__global__ __launch_bounds__(256) void k_noise0(const float* __restrict__ init,
    float* __restrict__ Y, unsigned ka, unsigned kb) {
  int idx = blockIdx.x * 256 + threadIdx.x;
  unsigned o0, o1;
  tf2x32(ka, kb, 0u, (unsigned)idx, o0, o1);
  float nz = noise_from_bits(o0 ^ o1);
  Y[idx] = fminf(fmaxf(init[idx] + nz, -1.0f), 1.0f);
}

// 2 pixels (along w) per thread; flow stencil in raw-x domain (80 folded into s1/EPS_S)
template <bool FINAL>
__global__ __launch_bounds__(256, 8) void k_step2(const float* __restrict__ X,
    float* __restrict__ Y, const float* __restrict__ in2,
    const float* __restrict__ sw, unsigned ka, unsigned kb) {
  int tid = blockIdx.x * 256 + threadIdx.x;   // [0, 8*HHW)
  int b = tid / HHW;
  int q = tid - b * HHW;
  int p = q * 2;                              // pixel base, even
  int h = p >> 9, w = p & 511;
  float s0 = sw[0], s1 = sw[1];
  const float* F0 = X + b * CHW;
  const float* F1 = F0 + HW;
  const bool wpos = (w > 0), wend = (w == 510);
  const bool hpos = (h > 0), hlast = (h == 383);

  // ---- flow stencil (raw x values); cf[c][2] duplicated at right edge so dx=0 ----
  float cf[2][3], fm1[2], dw[2][2], dwm1[2], uf[2][3];
  {
    float2 a0 = *(const float2*)(F0 + p);
    float2 a1 = *(const float2*)(F1 + p);
    cf[0][0] = a0.x; cf[0][1] = a0.y;
    cf[1][0] = a1.x; cf[1][1] = a1.y;
    cf[0][2] = wend ? cf[0][1] : F0[p + 2];
    cf[1][2] = wend ? cf[1][1] : F1[p + 2];
    fm1[0] = wpos ? F0[p - 1] : cf[0][0];
    fm1[1] = wpos ? F1[p - 1] : cf[1][0];
    if (!hlast) {
      float2 d0 = *(const float2*)(F0 + p + WW);
      float2 d1 = *(const float2*)(F1 + p + WW);
      dw[0][0] = d0.x; dw[0][1] = d0.y;
      dw[1][0] = d1.x; dw[1][1] = d1.y;
      dwm1[0] = wpos ? F0[p + WW - 1] : fm1[0];
      dwm1[1] = wpos ? F1[p + WW - 1] : fm1[1];
    } else {
#pragma unroll
      for (int c = 0; c < 2; ++c) {
        dw[c][0] = cf[c][0]; dw[c][1] = cf[c][1];   // dy = 0
        dwm1[c] = fm1[c];
      }
    }
    if (hpos) {
      float2 u0 = *(const float2*)(F0 + p - WW);
      float2 u1 = *(const float2*)(F1 + p - WW);
      uf[0][0] = u0.x; uf[0][1] = u0.y;
      uf[1][0] = u1.x; uf[1][1] = u1.y;
      uf[0][2] = wend ? uf[0][1] : F0[p - WW + 2];
      uf[1][2] = wend ? uf[1][1] : F1[p - WW + 2];
    } else {
#pragma unroll
      for (int c = 0; c < 2; ++c)
        for (int j = 0; j < 3; ++j) uf[c][j] = cf[c][j];   // unused (masked by hpos)
    }
  }

  // ---- shared S sites: SL = S(h,w-1); Sc[j] = S(h,w+j); Su[j] = S(h-1,w+j) ----
  float dxc[2][2], dyc[2][2], invSc[2], dxu[2][2], dyu[2][2], invSu[2];
  float dxl[2], dyl[2], invSL;
#pragma unroll
  for (int j = 0; j < 2; ++j) {
#pragma unroll
    for (int c = 0; c < 2; ++c) {
      dxc[c][j] = cf[c][j + 1] - cf[c][j];
      dyc[c][j] = dw[c][j] - cf[c][j];
      dxu[c][j] = uf[c][j + 1] - uf[c][j];
      dyu[c][j] = cf[c][j] - uf[c][j];
    }
    invSc[j] = rsq_f(dxc[0][j]*dxc[0][j] + dxc[1][j]*dxc[1][j]
                   + dyc[0][j]*dyc[0][j] + dyc[1][j]*dyc[1][j] + EPS_S);
    invSu[j] = rsq_f(dxu[0][j]*dxu[0][j] + dxu[1][j]*dxu[1][j]
                   + dyu[0][j]*dyu[0][j] + dyu[1][j]*dyu[1][j] + EPS_S);
  }
  dxl[0] = cf[0][0] - fm1[0];  dxl[1] = cf[1][0] - fm1[1];
  dyl[0] = dwm1[0] - fm1[0];   dyl[1] = dwm1[1] - fm1[1];
  invSL = rsq_f(dxl[0]*dxl[0] + dxl[1]*dxl[1]
              + dyl[0]*dyl[0] + dyl[1]*dyl[1] + EPS_S);

  // ---- flow grads + update ----
  float xnF[2][2];
#pragma unroll
  for (int j = 0; j < 2; ++j) {
#pragma unroll
    for (int c = 0; c < 2; ++c) {
      float g = -(dxc[c][j] + dyc[c][j]) * invSc[j];
      if (j == 0) { if (wpos) g += dxl[c] * invSL; }
      else        { g += dxc[c][0] * invSc[0]; }
      if (hpos)   { g += dyu[c][j] * invSu[j]; }
      xnF[c][j] = upd(cf[c][j], g * s1);
    }
  }

  // ---- img channels (pixel-local data term) ----
  const float* XI = F0 + 2 * HW;
  const float* I2 = in2 + b * 3 * HW;
  float xv[3][2], dI[3][2];
#pragma unroll
  for (int c = 0; c < 3; ++c) {
    float2 xvv = *(const float2*)(XI + c * HW + p);
    float2 ivv = *(const float2*)(I2 + c * HW + p);
    xv[c][0] = xvv.x; xv[c][1] = xvv.y;
    dI[c][0] = (xvv.x + 1.0f) * 0.5f - ((ivv.x * 2.0f - 1.0f) + 1.0f) * 0.5f;
    dI[c][1] = (xvv.y + 1.0f) * 0.5f - ((ivv.y * 2.0f - 1.0f) + 1.0f) * 0.5f;
  }
  float xnI[3][2];
#pragma unroll
  for (int j = 0; j < 2; ++j) {
    float A = dI[0][j]*dI[0][j] + dI[1][j]*dI[1][j] + dI[2][j]*dI[2][j];
    float sI = s0 * rsq_f(A + EPS_F);
#pragma unroll
    for (int c = 0; c < 3; ++c) xnI[c][j] = upd(xv[c][j], dI[c][j] * sI);
  }

  // ---- noise + store (or final transform) ----
  if (!FINAL) {
    int base = b * CHW + p;
    noise_store2(Y + base,      xnF[0], ka, kb, (unsigned)base);
    noise_store2(Y + base + HW, xnF[1], ka, kb, (unsigned)(base + HW));
#pragma unroll
    for (int c = 0; c < 3; ++c)
      noise_store2(Y + base + (2 + c) * HW, xnI[c], ka, kb,
                   (unsigned)(base + (2 + c) * HW));
  } else {
    float* outF = Y + OUT_FLOW_OFF + b * 2 * HW;
    *(float2*)(outF + p)      = make_float2(xnF[0][0]*80.f, xnF[0][1]*80.f);
    *(float2*)(outF + HW + p) = make_float2(xnF[1][0]*80.f, xnF[1][1]*80.f);
    float* outI = Y + OUT_IMG_OFF + b * 3 * HW;
#pragma unroll
    for (int c = 0; c < 3; ++c)
      *(float2*)(outI + c * HW + p) = make_float2((xnI[c][0]+1.f)*0.5f,
                                                  (xnI[c][1]+1.f)*0.5f);
  }
}

__device__ __forceinline__ void block_acc2(double v0, double v1, double* a0, double* a1) {
  for (int off = 32; off > 0; off >>= 1) {
    v0 += __shfl_down(v0, off, 64);
    v1 += __shfl_down(v1, off, 64);
  }
  __shared__ double s0m[4], s1m[4];
  int lane = threadIdx.x & 63, wv = threadIdx.x >> 6;
  if (lane == 0) { s0m[wv] = v0; s1m[wv] = v1; }
  __syncthreads();
  if (threadIdx.x == 0) {
    atomicAdd(a0, s0m[0] + s0m[1] + s0m[2] + s0m[3]);
    atomicAdd(a1, s1m[0] + s1m[1] + s1m[2] + s1m[3]);
  }
}

// 96 blocks per batch, each covering 8 contiguous 256-px chunks
__global__ __launch_bounds__(256) void k_pos_energy(const float* __restrict__ t1,
    const float* __restrict__ in1, const float* __restrict__ in2,
    double* __restrict__ acc) {
  int blk = blockIdx.x;
  int b = blk / 96;
  int local = blk - b * 96;
  const float* T0 = t1 + b * 2 * HW;
  const float* T1 = T0 + HW;
  const float* I1 = in1 + b * 3 * HW;
  const float* I2 = in2 + b * 3 * HW;
  double data = 0.0, smooth = 0.0;
  for (int it = 0; it < 8; ++it) {
    int p = (local * 8 + it) * 256 + threadIdx.x;
    int h = p >> 9, w = p & 511;
    float f00 = (T0[p] / 80.0f) * 80.0f;     // mirror (t/80)*80 roundtrip
    float f10 = (T1[p] / 80.0f) * 80.0f;
    float dx0 = 0, dx1 = 0, dy0 = 0, dy1 = 0;
    if (w < 511) { dx0 = (T0[p+1]/80.0f)*80.0f - f00;  dx1 = (T1[p+1]/80.0f)*80.0f - f10; }
    if (h < 383) { dy0 = (T0[p+WW]/80.0f)*80.0f - f00; dy1 = (T1[p+WW]/80.0f)*80.0f - f10; }
    smooth += (double)sqrtf(dx0*dx0 + dx1*dx1 + dy0*dy0 + dy1*dy1 + EPS_F);
    float d0 = ((I1[p]*2.0f-1.0f)+1.0f)*0.5f        - ((I2[p]*2.0f-1.0f)+1.0f)*0.5f;
    float d1 = ((I1[p+HW]*2.0f-1.0f)+1.0f)*0.5f     - ((I2[p+HW]*2.0f-1.0f)+1.0f)*0.5f;
    float d2 = ((I1[p+2*HW]*2.0f-1.0f)+1.0f)*0.5f   - ((I2[p+2*HW]*2.0f-1.0f)+1.0f)*0.5f;
    data += (double)sqrtf(d0*d0 + d1*d1 + d2*d2 + EPS_F);
  }
  block_acc2(data, smooth, &acc[b], &acc[8 + b]);
}

__global__ __launch_bounds__(256) void k_neg_energy(const float* __restrict__ out,
    const float* __restrict__ in2, double* __restrict__ acc) {
  int blk = blockIdx.x;
  int b = blk / 96;
  int local = blk - b * 96;
  const float* F0 = out + OUT_FLOW_OFF + b * 2 * HW;   // already = 80*x
  const float* F1 = F0 + HW;
  const float* I = out + OUT_IMG_OFF + b * 3 * HW;     // already = (x+1)/2
  const float* I2 = in2 + b * 3 * HW;
  double data = 0.0, smooth = 0.0;
  for (int it = 0; it < 8; ++it) {
    int p = (local * 8 + it) * 256 + threadIdx.x;
    int h = p >> 9, w = p & 511;
    float f00 = F0[p], f10 = F1[p];
    float dx0 = 0, dx1 = 0, dy0 = 0, dy1 = 0;
    if (w < 511) { dx0 = F0[p + 1] - f00;  dx1 = F1[p + 1] - f10; }
    if (h < 383) { dy0 = F0[p + WW] - f00; dy1 = F1[p + WW] - f10; }
    smooth += (double)sqrtf(dx0*dx0 + dx1*dx1 + dy0*dy0 + dy1*dy1 + EPS_F);
    float d0 = I[p]        - ((I2[p]*2.0f-1.0f)+1.0f)*0.5f;
    float d1 = I[p+HW]     - ((I2[p+HW]*2.0f-1.0f)+1.0f)*0.5f;
    float d2 = I[p+2*HW]   - ((I2[p+2*HW]*2.0f-1.0f)+1.0f)*0.5f;
    data += (double)sqrtf(d0*d0 + d1*d1 + d2*d2 + EPS_F);
  }
  block_acc2(data, smooth, &acc[16 + b], &acc[24 + b]);
}

__global__ void k_finalize(const double* __restrict__ acc,
                           const float* __restrict__ lw, float* __restrict__ out) {
  int t = threadIdx.x;
  if (t < 16) {
    int b = t & 7, neg = t >> 3;
    double data   = acc[neg * 16 + b];
    double smooth = acc[neg * 16 + 8 + b];
    double e0 = exp((double)lw[0]), e1 = exp((double)lw[1]);
    out[t] = (float)((e0 * data + e1 * smooth) / 196608.0);
  }
}

extern "C" void kernel_launch(void* const* d_in, const int* in_sizes, int n_in,
                              void* d_out, int out_size, void* d_ws, size_t ws_size,
                              hipStream_t stream) {
  const float* t1  = (const float*)d_in[0];
  const float* in1 = (const float*)d_in[1];
  const float* in2 = (const float*)d_in[2];
  const float* init = (const float*)d_in[3];
  const float* lw  = (const float*)d_in[4];
  float* out = (float*)d_out;

  double* acc = (double*)d_ws;                          // 32 doubles
  float* sw = (float*)((char*)d_ws + 256);              // 2 floats
  size_t need = 2048 + (size_t)NTOT * sizeof(float);
  float* bufA = (ws_size >= need) ? (float*)((char*)d_ws + 2048)
                                  : (float*)d_in[3];    // fallback: reuse init
  float* bufE = out + OUT_FLOW_OFF;                     // even-t states live in d_out

  // host-side threefry split: keys[t] = tf(0,1,0,t)  (pure integer function)
  unsigned K0[200], K1[200];
  for (int t = 0; t < 200; ++t) tf2x32(0u, 1u, 0u, (unsigned)t, K0[t], K1[t]);

  k_init<<<1, 64, 0, stream>>>(acc, sw, lw);
  k_pos_energy<<<8 * 96, 256, 0, stream>>>(t1, in1, in2, acc);
  k_noise0<<<NTOT / 256, 256, 0, stream>>>(init, bufE, K0[0], K1[0]);   // n_0 (even)
  for (int t = 0; t < 199; ++t) {
    const float* src = (t % 2 == 0) ? bufE : bufA;
    float* dst       = (t % 2 == 0) ? bufA : bufE;
    k_step2<false><<<8 * HHW / 256, 256, 0, stream>>>(src, dst, in2, sw,
                                                      K0[t + 1], K1[t + 1]);
  }
  // n_199 is in bufA (odd); final grad step writes transformed outputs
  k_step2<true><<<8 * HHW / 256, 256, 0, stream>>>(bufA, out, in2, sw, 0u, 0u);
  k_neg_energy<<<8 * 96, 256, 0, stream>>>(out, in2, acc);
  k_finalize<<<1, 64, 0, stream>>>(acc, lw, out);
}

// Round 5
// 5321.947 us; speedup vs baseline: 1.9258x; 1.0370x over previous
//
#include <hip/hip_runtime.h>
#include <math.h>

#define HH 384
#define WW 512
#define HW 196608            // 384*512
#define HHW 98304            // HW/2
#define CHW 983040           // 5*HW
#define NTOT 7864320         // 8*CHW
#define FLOW_N 3145728       // 8*2*HW
#define OUT_FLOW_OFF 16
#define OUT_IMG_OFF (16 + FLOW_N)
#define EPS_F 1e-5f
#define EPS_S (1e-5f / 6400.0f)   // smooth-term eps in raw-x domain (S is deg-1 homog in 80x)
#define INV_HW (1.0f/196608.0f)

// single-instruction HW transcendentals (v_rsq_f32 / v_log_f32 / v_sqrt_f32, ~1 ulp)
__device__ __forceinline__ float rsq_f(float x)  { return __builtin_amdgcn_rsqf(x); }
__device__ __forceinline__ float ln_f(float x)   { return 0.69314718055994531f * __builtin_amdgcn_logf(x); }
__device__ __forceinline__ float sqrt_f(float x) { return __builtin_amdgcn_sqrtf(x); }

// ---- JAX threefry2x32 (bit-exact integer path), host+device ----
__host__ __device__ __forceinline__ void tf2x32(unsigned k0, unsigned k1,
                                                unsigned x0, unsigned x1,
                                                unsigned& o0, unsigned& o1) {
  const unsigned ks2 = k0 ^ k1 ^ 0x1BD11BDAu;
  x0 += k0; x1 += k1;
#define TFR(r) x0 += x1; x1 = (x1 << (r)) | (x1 >> (32 - (r))); x1 ^= x0;
  TFR(13) TFR(15) TFR(26) TFR(6)
  x0 += k1;  x1 += ks2 + 1u;
  TFR(17) TFR(29) TFR(16) TFR(24)
  x0 += ks2; x1 += k0 + 2u;
  TFR(13) TFR(15) TFR(26) TFR(6)
  x0 += k0;  x1 += k1 + 3u;
  TFR(17) TFR(29) TFR(16) TFR(24)
  x0 += k1;  x1 += ks2 + 4u;
  TFR(13) TFR(15) TFR(26) TFR(6)
  x0 += ks2; x1 += k0 + 5u;
#undef TFR
  o0 = x0; o1 = x1;
}

// bits -> NOISE_STD * sqrt(2) * erfinv(uniform(lo,1))   (JAX normal * 0.05)
__device__ __forceinline__ float noise_from_bits(unsigned bits) {
  const float LO = -0.99999994f;                    // nextafter(-1,0)
  float f = __uint_as_float((bits >> 9) | 0x3F800000u) - 1.0f;  // [0,1)
  float u = fmaxf(LO, f * 2.0f + LO);               // (hi-lo) rounds to 2.0f
  // -log1p(-u^2) via factored form (accurate near |u|~1) + HW log
  float w = -ln_f((1.0f - u) * (1.0f + u));
  float p;
  if (w < 5.0f) {
    w -= 2.5f;
    p = 2.81022636e-08f;
    p = p * w + 3.43273939e-07f;
    p = p * w + -3.5233877e-06f;
    p = p * w + -4.39150654e-06f;
    p = p * w + 0.00021858087f;
    p = p * w + -0.00125372503f;
    p = p * w + -0.00417768164f;
    p = p * w + 0.246640727f;
    p = p * w + 1.50140941f;
  } else {
    w = sqrt_f(w) - 3.0f;
    p = -0.000200214257f;
    p = p * w + 0.000100950558f;
    p = p * w + 0.00134934322f;
    p = p * w + -0.00367342844f;
    p = p * w + 0.00573950773f;
    p = p * w + -0.0076224613f;
    p = p * w + 0.00943887047f;
    p = p * w + 1.00167406f;
    p = p * w + 2.83297682f;
  }
  float z = 1.4142135623730951f * (p * u);
  return 0.05f * z;
}

__device__ __forceinline__ float upd(float x, float g) {
  g = fminf(fmaxf(g, -0.03f), 0.03f);
  return fminf(fmaxf(x - 10.0f * g, -1.0f), 1.0f);
}

__device__ __forceinline__ float noise_at(unsigned ka, unsigned kb, unsigned idx) {
  unsigned o0, o1;
  tf2x32(ka, kb, 0u, idx, o0, o1);
  return noise_from_bits(o0 ^ o1);
}

// add noise to 2 results and store as float2 (non-final path)
__device__ __forceinline__ void noise_store2(float* dst, const float xn[2],
                                             unsigned ka, unsigned kb, unsigned idx0) {
  float r0 = fminf(fmaxf(xn[0] + noise_at(ka, kb, idx0), -1.0f), 1.0f);
  float r1 = fminf(fmaxf(xn[1] + noise_at(ka, kb, idx0 + 1u), -1.0f), 1.0f);
  *(float2*)dst = make_float2(r0, r1);
}

// ---- kernels ----
__global__ void k_init(double* acc, float* sw, const float* lw) {
  int t = threadIdx.x;
  if (t < 32) acc[t] = 0.0;
  if (t == 32) {
    sw[0] = expf(lw[0]) * INV_HW * 0.5f;    // data-term scale
    sw[1] = expf(lw[1]) * INV_HW * 80.0f;   // smooth-term scale (incl d(flow)/dx = 80)
  }
}

// flow noise_0: compact (B,2,H,W) buffer, noise indexed in original 5-ch layout
__global__ __launch_bounds__(256) void k_fnoise0(const float* __restrict__ init,
    float* __restrict__ Y, unsigned ka, unsigned kb) {
  int e = blockIdx.x * 256 + threadIdx.x;    // [0, FLOW_N)
  int b = e / (2 * HW);
  int r = e - b * 2 * HW;
  int orig = b * CHW + r;                    // original element index (channels 0..1)
  float nz = noise_at(ka, kb, (unsigned)orig);
  Y[e] = fminf(fmaxf(init[orig] + nz, -1.0f), 1.0f);
}

// flow grad step (2 px/thread); state compact (B,2,H,W); raw-x domain
template <bool FINAL>
__global__ __launch_bounds__(256, 8) void k_fstep(const float* __restrict__ X,
    float* __restrict__ Y, const float* __restrict__ sw,
    unsigned ka, unsigned kb) {
  int tid = blockIdx.x * 256 + threadIdx.x;   // [0, 8*HHW)
  int b = tid / HHW;
  int q = tid - b * HHW;
  int p = q * 2;                              // pixel base, even
  int h = p >> 9, w = p & 511;
  float s1 = sw[1];
  const float* F0 = X + b * 2 * HW;
  const float* F1 = F0 + HW;
  const bool wpos = (w > 0), wend = (w == 510);
  const bool hpos = (h > 0), hlast = (h == 383);

  // ---- flow stencil (raw x values); cf[c][2] duplicated at right edge so dx=0 ----
  float cf[2][3], fm1[2], dw[2][2], dwm1[2], uf[2][3];
  {
    float2 a0 = *(const float2*)(F0 + p);
    float2 a1 = *(const float2*)(F1 + p);
    cf[0][0] = a0.x; cf[0][1] = a0.y;
    cf[1][0] = a1.x; cf[1][1] = a1.y;
    cf[0][2] = wend ? cf[0][1] : F0[p + 2];
    cf[1][2] = wend ? cf[1][1] : F1[p + 2];
    fm1[0] = wpos ? F0[p - 1] : cf[0][0];
    fm1[1] = wpos ? F1[p - 1] : cf[1][0];
    if (!hlast) {
      float2 d0 = *(const float2*)(F0 + p + WW);
      float2 d1 = *(const float2*)(F1 + p + WW);
      dw[0][0] = d0.x; dw[0][1] = d0.y;
      dw[1][0] = d1.x; dw[1][1] = d1.y;
      dwm1[0] = wpos ? F0[p + WW - 1] : fm1[0];
      dwm1[1] = wpos ? F1[p + WW - 1] : fm1[1];
    } else {
#pragma unroll
      for (int c = 0; c < 2; ++c) {
        dw[c][0] = cf[c][0]; dw[c][1] = cf[c][1];   // dy = 0
        dwm1[c] = fm1[c];
      }
    }
    if (hpos) {
      float2 u0 = *(const float2*)(F0 + p - WW);
      float2 u1 = *(const float2*)(F1 + p - WW);
      uf[0][0] = u0.x; uf[0][1] = u0.y;
      uf[1][0] = u1.x; uf[1][1] = u1.y;
      uf[0][2] = wend ? uf[0][1] : F0[p - WW + 2];
      uf[1][2] = wend ? uf[1][1] : F1[p - WW + 2];
    } else {
#pragma unroll
      for (int c = 0; c < 2; ++c)
        for (int j = 0; j < 3; ++j) uf[c][j] = cf[c][j];   // unused (masked by hpos)
    }
  }

  // ---- shared S sites: SL = S(h,w-1); Sc[j] = S(h,w+j); Su[j] = S(h-1,w+j) ----
  float dxc[2][2], dyc[2][2], invSc[2], dxu[2][2], dyu[2][2], invSu[2];
  float dxl[2], dyl[2], invSL;
#pragma unroll
  for (int j = 0; j < 2; ++j) {
#pragma unroll
    for (int c = 0; c < 2; ++c) {
      dxc[c][j] = cf[c][j + 1] - cf[c][j];
      dyc[c][j] = dw[c][j] - cf[c][j];
      dxu[c][j] = uf[c][j + 1] - uf[c][j];
      dyu[c][j] = cf[c][j] - uf[c][j];
    }
    invSc[j] = rsq_f(dxc[0][j]*dxc[0][j] + dxc[1][j]*dxc[1][j]
                   + dyc[0][j]*dyc[0][j] + dyc[1][j]*dyc[1][j] + EPS_S);
    invSu[j] = rsq_f(dxu[0][j]*dxu[0][j] + dxu[1][j]*dxu[1][j]
                   + dyu[0][j]*dyu[0][j] + dyu[1][j]*dyu[1][j] + EPS_S);
  }
  dxl[0] = cf[0][0] - fm1[0];  dxl[1] = cf[1][0] - fm1[1];
  dyl[0] = dwm1[0] - fm1[0];   dyl[1] = dwm1[1] - fm1[1];
  invSL = rsq_f(dxl[0]*dxl[0] + dxl[1]*dxl[1]
              + dyl[0]*dyl[0] + dyl[1]*dyl[1] + EPS_S);

  // ---- flow grads + update ----
  float xnF[2][2];
#pragma unroll
  for (int j = 0; j < 2; ++j) {
#pragma unroll
    for (int c = 0; c < 2; ++c) {
      float g = -(dxc[c][j] + dyc[c][j]) * invSc[j];
      if (j == 0) { if (wpos) g += dxl[c] * invSL; }
      else        { g += dxc[c][0] * invSc[0]; }
      if (hpos)   { g += dyu[c][j] * invSu[j]; }
      xnF[c][j] = upd(cf[c][j], g * s1);
    }
  }

  // ---- noise + store (or final transform) ----
  if (!FINAL) {
    int nbase = b * CHW + p;                 // noise index in original 5-ch layout
    int sb = b * 2 * HW + p;                 // compact store index
    noise_store2(Y + sb,      xnF[0], ka, kb, (unsigned)nbase);
    noise_store2(Y + sb + HW, xnF[1], ka, kb, (unsigned)(nbase + HW));
  } else {
    float* outF = Y + OUT_FLOW_OFF + b * 2 * HW;
    *(float2*)(outF + p)      = make_float2(xnF[0][0]*80.f, xnF[0][1]*80.f);
    *(float2*)(outF + HW + p) = make_float2(xnF[1][0]*80.f, xnF[1][1]*80.f);
  }
}

// img channels: per-pixel independent 200-step recurrence, state in registers.
// data term is pixel-local and flow-independent (energy is separable), so no
// global traffic / sync inside the loop. Arithmetic order identical to k_step2.
__global__ __launch_bounds__(256, 8) void k_img(const float* __restrict__ init,
    const float* __restrict__ in2, const float* __restrict__ sw,
    float* __restrict__ out) {
  __shared__ unsigned Kl[400];
  int tid = threadIdx.x;
  if (tid < 200) {                            // split(key(1),200): tf(0,1,0,t)
    unsigned a, bb;
    tf2x32(0u, 1u, 0u, (unsigned)tid, a, bb);
    Kl[2 * tid] = a; Kl[2 * tid + 1] = bb;
  }
  __syncthreads();
  int g = blockIdx.x * 256 + tid;             // [0, 8*HW)
  int b = g / HW;
  int p = g - b * HW;
  float s0 = sw[0];
  unsigned base = (unsigned)(b * CHW + 2 * HW + p);   // channel-2 noise index
  // init state (channels 2..4 of (B,5,H,W))
  float x0 = init[base], x1 = init[base + HW], x2 = init[base + 2 * HW];
  // img2 fp round-trip, loop-invariant: ((i*2-1)+1)*0.5
  const float* I2 = in2 + b * 3 * HW + p;
  float i0 = ((I2[0] * 2.0f - 1.0f) + 1.0f) * 0.5f;
  float i1 = ((I2[HW] * 2.0f - 1.0f) + 1.0f) * 0.5f;
  float i2v = ((I2[2 * HW] * 2.0f - 1.0f) + 1.0f) * 0.5f;

  for (int t = 0; t < 200; ++t) {
    unsigned ka = Kl[2 * t], kb = Kl[2 * t + 1];
    x0 = fminf(fmaxf(x0 + noise_at(ka, kb, base), -1.0f), 1.0f);
    x1 = fminf(fmaxf(x1 + noise_at(ka, kb, base + HW), -1.0f), 1.0f);
    x2 = fminf(fmaxf(x2 + noise_at(ka, kb, base + 2 * HW), -1.0f), 1.0f);
    float d0 = (x0 + 1.0f) * 0.5f - i0;
    float d1 = (x1 + 1.0f) * 0.5f - i1;
    float d2 = (x2 + 1.0f) * 0.5f - i2v;
    float A = d0*d0 + d1*d1 + d2*d2;
    float sI = s0 * rsq_f(A + EPS_F);
    x0 = upd(x0, d0 * sI);
    x1 = upd(x1, d1 * sI);
    x2 = upd(x2, d2 * sI);
  }
  float* outI = out + OUT_IMG_OFF + b * 3 * HW + p;
  outI[0]      = (x0 + 1.0f) * 0.5f;
  outI[HW]     = (x1 + 1.0f) * 0.5f;
  outI[2 * HW] = (x2 + 1.0f) * 0.5f;
}

__device__ __forceinline__ void block_acc2(double v0, double v1, double* a0, double* a1) {
  for (int off = 32; off > 0; off >>= 1) {
    v0 += __shfl_down(v0, off, 64);
    v1 += __shfl_down(v1, off, 64);
  }
  __shared__ double s0m[4], s1m[4];
  int lane = threadIdx.x & 63, wv = threadIdx.x >> 6;
  if (lane == 0) { s0m[wv] = v0; s1m[wv] = v1; }
  __syncthreads();
  if (threadIdx.x == 0) {
    atomicAdd(a0, s0m[0] + s0m[1] + s0m[2] + s0m[3]);
    atomicAdd(a1, s1m[0] + s1m[1] + s1m[2] + s1m[3]);
  }
}

// 96 blocks per batch, each covering 8 contiguous 256-px chunks
__global__ __launch_bounds__(256) void k_pos_energy(const float* __restrict__ t1,
    const float* __restrict__ in1, const float* __restrict__ in2,
    double* __restrict__ acc) {
  int blk = blockIdx.x;
  int b = blk / 96;
  int local = blk - b * 96;
  const float* T0 = t1 + b * 2 * HW;
  const float* T1 = T0 + HW;
  const float* I1 = in1 + b * 3 * HW;
  const float* I2 = in2 + b * 3 * HW;
  double data = 0.0, smooth = 0.0;
  for (int it = 0; it < 8; ++it) {
    int p = (local * 8 + it) * 256 + threadIdx.x;
    int h = p >> 9, w = p & 511;
    float f00 = (T0[p] / 80.0f) * 80.0f;     // mirror (t/80)*80 roundtrip
    float f10 = (T1[p] / 80.0f) * 80.0f;
    float dx0 = 0, dx1 = 0, dy0 = 0, dy1 = 0;
    if (w < 511) { dx0 = (T0[p+1]/80.0f)*80.0f - f00;  dx1 = (T1[p+1]/80.0f)*80.0f - f10; }
    if (h < 383) { dy0 = (T0[p+WW]/80.0f)*80.0f - f00; dy1 = (T1[p+WW]/80.0f)*80.0f - f10; }
    smooth += (double)sqrtf(dx0*dx0 + dx1*dx1 + dy0*dy0 + dy1*dy1 + EPS_F);
    float d0 = ((I1[p]*2.0f-1.0f)+1.0f)*0.5f        - ((I2[p]*2.0f-1.0f)+1.0f)*0.5f;
    float d1 = ((I1[p+HW]*2.0f-1.0f)+1.0f)*0.5f     - ((I2[p+HW]*2.0f-1.0f)+1.0f)*0.5f;
    float d2 = ((I1[p+2*HW]*2.0f-1.0f)+1.0f)*0.5f   - ((I2[p+2*HW]*2.0f-1.0f)+1.0f)*0.5f;
    data += (double)sqrtf(d0*d0 + d1*d1 + d2*d2 + EPS_F);
  }
  block_acc2(data, smooth, &acc[b], &acc[8 + b]);
}

__global__ __launch_bounds__(256) void k_neg_energy(const float* __restrict__ out,
    const float* __restrict__ in2, double* __restrict__ acc) {
  int blk = blockIdx.x;
  int b = blk / 96;
  int local = blk - b * 96;
  const float* F0 = out + OUT_FLOW_OFF + b * 2 * HW;   // already = 80*x
  const float* F1 = F0 + HW;
  const float* I = out + OUT_IMG_OFF + b * 3 * HW;     // already = (x+1)/2
  const float* I2 = in2 + b * 3 * HW;
  double data = 0.0, smooth = 0.0;
  for (int it = 0; it < 8; ++it) {
    int p = (local * 8 + it) * 256 + threadIdx.x;
    int h = p >> 9, w = p & 511;
    float f00 = F0[p], f10 = F1[p];
    float dx0 = 0, dx1 = 0, dy0 = 0, dy1 = 0;
    if (w < 511) { dx0 = F0[p + 1] - f00;  dx1 = F1[p + 1] - f10; }
    if (h < 383) { dy0 = F0[p + WW] - f00; dy1 = F1[p + WW] - f10; }
    smooth += (double)sqrtf(dx0*dx0 + dx1*dx1 + dy0*dy0 + dy1*dy1 + EPS_F);
    float d0 = I[p]        - ((I2[p]*2.0f-1.0f)+1.0f)*0.5f;
    float d1 = I[p+HW]     - ((I2[p+HW]*2.0f-1.0f)+1.0f)*0.5f;
    float d2 = I[p+2*HW]   - ((I2[p+2*HW]*2.0f-1.0f)+1.0f)*0.5f;
    data += (double)sqrtf(d0*d0 + d1*d1 + d2*d2 + EPS_F);
  }
  block_acc2(data, smooth, &acc[16 + b], &acc[24 + b]);
}

__global__ void k_finalize(const double* __restrict__ acc,
                           const float* __restrict__ lw, float* __restrict__ out) {
  int t = threadIdx.x;
  if (t < 16) {
    int b = t & 7, neg = t >> 3;
    double data   = acc[neg * 16 + b];
    double smooth = acc[neg * 16 + 8 + b];
    double e0 = exp((double)lw[0]), e1 = exp((double)lw[1]);
    out[t] = (float)((e0 * data + e1 * smooth) / 196608.0);
  }
}

extern "C" void kernel_launch(void* const* d_in, const int* in_sizes, int n_in,
                              void* d_out, int out_size, void* d_ws, size_t ws_size,
                              hipStream_t stream) {
  const float* t1  = (const float*)d_in[0];
  const float* in1 = (const float*)d_in[1];
  const float* in2 = (const float*)d_in[2];
  const float* init = (const float*)d_in[3];
  const float* lw  = (const float*)d_in[4];
  float* out = (float*)d_out;

  double* acc = (double*)d_ws;                          // 32 doubles
  float* sw = (float*)((char*)d_ws + 256);              // 2 floats
  float* bufFA = (float*)((char*)d_ws + 2048);          // flow ping (12.6 MB)
  size_t need = 2048 + 2 * (size_t)FLOW_N * sizeof(float);
  float* bufFB = (ws_size >= need) ? bufFA + FLOW_N
                                   : out + OUT_FLOW_OFF;  // fallback: d_out flow region

  // host-side threefry split: keys[t] = tf(0,1,0,t)  (pure integer function)
  unsigned K0[200], K1[200];
  for (int t = 0; t < 200; ++t) tf2x32(0u, 1u, 0u, (unsigned)t, K0[t], K1[t]);

  k_init<<<1, 64, 0, stream>>>(acc, sw, lw);
  k_pos_energy<<<8 * 96, 256, 0, stream>>>(t1, in1, in2, acc);

  // ---- flow trajectory: noise_0 into bufFB, then grad_t(+noise_{t+1}) ping-pong;
  //      parity chosen so the FINAL step (t=199, odd) reads bufFA (never aliases out)
  k_fnoise0<<<FLOW_N / 256, 256, 0, stream>>>(init, bufFB, K0[0], K1[0]);
  for (int t = 0; t < 199; ++t) {
    const float* src = (t % 2 == 0) ? bufFB : bufFA;
    float* dst       = (t % 2 == 0) ? bufFA : bufFB;
    k_fstep<false><<<8 * HHW / 256, 256, 0, stream>>>(src, dst, sw,
                                                      K0[t + 1], K1[t + 1]);
  }
  k_fstep<true><<<8 * HHW / 256, 256, 0, stream>>>(bufFA, out, sw, 0u, 0u);

  // ---- img trajectory: one persistent kernel, all 200 steps in registers
  k_img<<<8 * HW / 256, 256, 0, stream>>>(init, in2, sw, out);

  k_neg_energy<<<8 * 96, 256, 0, stream>>>(out, in2, acc);
  k_finalize<<<1, 64, 0, stream>>>(acc, lw, out);
}

// Round 6
// 5264.621 us; speedup vs baseline: 1.9468x; 1.0109x over previous
//
#include <hip/hip_runtime.h>
#include <math.h>

#define HH 384
#define WW 512
#define HW 196608            // 384*512
#define CHW 983040           // 5*HW
#define NTOT 7864320         // 8*CHW
#define FLOW_N 3145728       // 8*2*HW
#define OUT_FLOW_OFF 16
#define OUT_IMG_OFF (16 + FLOW_N)
#define EPS_F 1e-5f
#define EPS_S (1e-5f / 6400.0f)   // smooth-term eps in raw-x domain (S is deg-1 homog in 80x)
#define INV_HW (1.0f/196608.0f)

// single-instruction HW transcendentals (v_rsq_f32 / v_log_f32 / v_sqrt_f32, ~1 ulp)
__device__ __forceinline__ float rsq_f(float x)  { return __builtin_amdgcn_rsqf(x); }
__device__ __forceinline__ float ln_f(float x)   { return 0.69314718055994531f * __builtin_amdgcn_logf(x); }
__device__ __forceinline__ float sqrt_f(float x) { return __builtin_amdgcn_sqrtf(x); }

// ---- JAX threefry2x32 (bit-exact integer path), host+device ----
__host__ __device__ __forceinline__ void tf2x32(unsigned k0, unsigned k1,
                                                unsigned x0, unsigned x1,
                                                unsigned& o0, unsigned& o1) {
  const unsigned ks2 = k0 ^ k1 ^ 0x1BD11BDAu;
  x0 += k0; x1 += k1;
#define TFR(r) x0 += x1; x1 = (x1 << (r)) | (x1 >> (32 - (r))); x1 ^= x0;
  TFR(13) TFR(15) TFR(26) TFR(6)
  x0 += k1;  x1 += ks2 + 1u;
  TFR(17) TFR(29) TFR(16) TFR(24)
  x0 += ks2; x1 += k0 + 2u;
  TFR(13) TFR(15) TFR(26) TFR(6)
  x0 += k0;  x1 += k1 + 3u;
  TFR(17) TFR(29) TFR(16) TFR(24)
  x0 += k1;  x1 += ks2 + 4u;
  TFR(13) TFR(15) TFR(26) TFR(6)
  x0 += ks2; x1 += k0 + 5u;
#undef TFR
  o0 = x0; o1 = x1;
}

// bits -> NOISE_STD * sqrt(2) * erfinv(uniform(lo,1))   (JAX normal * 0.05)
__device__ __forceinline__ float noise_from_bits(unsigned bits) {
  const float LO = -0.99999994f;                    // nextafter(-1,0)
  float f = __uint_as_float((bits >> 9) | 0x3F800000u) - 1.0f;  // [0,1)
  float u = fmaxf(LO, f * 2.0f + LO);               // (hi-lo) rounds to 2.0f
  // -log1p(-u^2) via factored form (accurate near |u|~1) + HW log
  float w = -ln_f((1.0f - u) * (1.0f + u));
  float p;
  if (w < 5.0f) {
    w -= 2.5f;
    p = 2.81022636e-08f;
    p = p * w + 3.43273939e-07f;
    p = p * w + -3.5233877e-06f;
    p = p * w + -4.39150654e-06f;
    p = p * w + 0.00021858087f;
    p = p * w + -0.00125372503f;
    p = p * w + -0.00417768164f;
    p = p * w + 0.246640727f;
    p = p * w + 1.50140941f;
  } else {
    w = sqrt_f(w) - 3.0f;
    p = -0.000200214257f;
    p = p * w + 0.000100950558f;
    p = p * w + 0.00134934322f;
    p = p * w + -0.00367342844f;
    p = p * w + 0.00573950773f;
    p = p * w + -0.0076224613f;
    p = p * w + 0.00943887047f;
    p = p * w + 1.00167406f;
    p = p * w + 2.83297682f;
  }
  float z = 1.4142135623730951f * (p * u);
  return 0.05f * z;
}

__device__ __forceinline__ float upd(float x, float g) {
  g = fminf(fmaxf(g, -0.03f), 0.03f);
  return fminf(fmaxf(x - 10.0f * g, -1.0f), 1.0f);
}

__device__ __forceinline__ float noise_at(unsigned ka, unsigned kb, unsigned idx) {
  unsigned o0, o1;
  tf2x32(ka, kb, 0u, idx, o0, o1);
  return noise_from_bits(o0 ^ o1);
}

__device__ __forceinline__ float clip1(float x) {
  return fminf(fmaxf(x, -1.0f), 1.0f);
}

// ---- kernels ----
__global__ void k_init(double* acc, float* sw, const float* lw) {
  int t = threadIdx.x;
  if (t < 32) acc[t] = 0.0;
  if (t == 32) {
    sw[0] = expf(lw[0]) * INV_HW * 0.5f;    // data-term scale
    sw[1] = expf(lw[1]) * INV_HW * 80.0f;   // smooth-term scale (incl d(flow)/dx = 80)
  }
}

// flow noise_0: compact (B,2,H,W) buffer, noise indexed in original 5-ch layout
__global__ __launch_bounds__(256) void k_fnoise0(const float* __restrict__ init,
    float* __restrict__ Y, unsigned ka, unsigned kb) {
  int e = blockIdx.x * 256 + threadIdx.x;    // [0, FLOW_N)
  int b = e / (2 * HW);
  int r = e - b * 2 * HW;
  int orig = b * CHW + r;                    // original element index (channels 0..1)
  float nz = noise_at(ka, kb, (unsigned)orig);
  Y[e] = clip1(init[orig] + nz);
}

// ---- flow double-step: T=2 temporal blocking, 32x32 output tile per block ----
// in-buf 36x36 (clamp-loaded halos), mid-buf 34x34 via LDS. Border semantics are
// preserved EXACTLY: clamped halo duplicates make every skipped boundary term an
// exact +0.0 (numerator is 0), and step-2 uses index-clamped lookups so garbage
// out-of-image mid-sites are never read. Trajectory is bit-identical to the
// single-step kernel. Redundant work: (34^2+32^2)/(2*32^2) = 1.064.
template <bool FINAL>
__global__ __launch_bounds__(256) void k_f2(const float* __restrict__ X,
    float* __restrict__ Y, const float* __restrict__ sw,
    unsigned kA0, unsigned kA1, unsigned kB0, unsigned kB1) {
  __shared__ float S0[2][36 * 36];   // 10.4 KB
  __shared__ float S1[2][34 * 34];   // 9.2 KB
  const int tid = threadIdx.x;
  const int bid = blockIdx.x;                 // [0, 1536)
  const int b  = bid / 192;
  const int rr = bid - b * 192;
  const int h0 = (rr / 16) * 32;
  const int w0 = (rr & 15) * 32;
  const float s1v = sw[1];
  const float* Fb = X + b * 2 * HW;

  // ---- load 36x36 (+2-ring, clamp-loaded) per channel ----
#pragma unroll
  for (int ch = 0; ch < 2; ++ch) {
    const float* F = Fb + ch * HW;
    for (int idx = tid; idx < 1296; idx += 256) {
      int i = idx / 36, j = idx - i * 36;
      int gh = min(max(h0 + i - 2, 0), 383);
      int gw = min(max(w0 + j - 2, 0), 511);
      S0[ch][idx] = F[gh * 512 + gw];
    }
  }
  __syncthreads();

  // ---- step A: compute 34x34 mid region (raw local stencil reads) + noise kA ----
  for (int r = tid; r < 1156; r += 256) {
    int i = r / 34, j = r - i * 34;
    int c00 = (i + 1) * 36 + (j + 1);
    float C0 = S0[0][c00],      C1 = S0[1][c00];
    float R0 = S0[0][c00 + 1],  R1 = S0[1][c00 + 1];
    float L0 = S0[0][c00 - 1],  L1 = S0[1][c00 - 1];
    float D0 = S0[0][c00 + 36], D1 = S0[1][c00 + 36];
    float U0 = S0[0][c00 - 36], U1 = S0[1][c00 - 36];
    float DL0 = S0[0][c00 + 35], DL1 = S0[1][c00 + 35];
    float UR0 = S0[0][c00 - 35], UR1 = S0[1][c00 - 35];
    float dxc0 = R0 - C0, dxc1 = R1 - C1;
    float dyc0 = D0 - C0, dyc1 = D1 - C1;
    float invSc = rsq_f(dxc0*dxc0 + dxc1*dxc1 + dyc0*dyc0 + dyc1*dyc1 + EPS_S);
    float dxl0 = C0 - L0, dxl1 = C1 - L1;
    float dyl0 = DL0 - L0, dyl1 = DL1 - L1;
    float invSL = rsq_f(dxl0*dxl0 + dxl1*dxl1 + dyl0*dyl0 + dyl1*dyl1 + EPS_S);
    float dxu0 = UR0 - U0, dxu1 = UR1 - U1;
    float dyu0 = C0 - U0, dyu1 = C1 - U1;
    float invSu = rsq_f(dxu0*dxu0 + dxu1*dxu1 + dyu0*dyu0 + dyu1*dyu1 + EPS_S);
    float g0 = -(dxc0 + dyc0) * invSc;
    g0 += dxl0 * invSL;
    g0 += dyu0 * invSu;
    float g1 = -(dxc1 + dyc1) * invSc;
    g1 += dxl1 * invSL;
    g1 += dyu1 * invSu;
    float x0 = upd(C0, g0 * s1v);
    float x1 = upd(C1, g1 * s1v);
    int gh = h0 + i - 1, gw = w0 + j - 1;   // may be out-of-image: noise/value garbage-ok (never read)
    unsigned nidx = (unsigned)(b * CHW + gh * 512 + gw);
    S1[0][r] = clip1(x0 + noise_at(kA0, kA1, nidx));
    S1[1][r] = clip1(x1 + noise_at(kA0, kA1, nidx + (unsigned)HW));
  }
  __syncthreads();

  // ---- step B: compute 32x32 output (index-clamped lookups) ----
  for (int r = tid; r < 1024; r += 256) {
    int i = r >> 5, j = r & 31;
    int gh = h0 + i, gw = w0 + j;
    int ii = i + 1, jj = j + 1;
    int iu = (gh > 0)   ? ii - 1 : ii;
    int id = (gh < 383) ? ii + 1 : ii;
    int jl = (gw > 0)   ? jj - 1 : jj;
    int jr = (gw < 511) ? jj + 1 : jj;
    int cC = ii * 34 + jj;
    int cR = ii * 34 + jr, cL = ii * 34 + jl;
    int cD = id * 34 + jj, cU = iu * 34 + jj;
    int cDL = id * 34 + jl, cUR = iu * 34 + jr;
    float C0 = S1[0][cC],  C1 = S1[1][cC];
    float R0 = S1[0][cR],  R1 = S1[1][cR];
    float L0 = S1[0][cL],  L1 = S1[1][cL];
    float D0 = S1[0][cD],  D1 = S1[1][cD];
    float U0 = S1[0][cU],  U1 = S1[1][cU];
    float DL0 = S1[0][cDL], DL1 = S1[1][cDL];
    float UR0 = S1[0][cUR], UR1 = S1[1][cUR];
    float dxc0 = R0 - C0, dxc1 = R1 - C1;
    float dyc0 = D0 - C0, dyc1 = D1 - C1;
    float invSc = rsq_f(dxc0*dxc0 + dxc1*dxc1 + dyc0*dyc0 + dyc1*dyc1 + EPS_S);
    float dxl0 = C0 - L0, dxl1 = C1 - L1;
    float dyl0 = DL0 - L0, dyl1 = DL1 - L1;
    float invSL = rsq_f(dxl0*dxl0 + dxl1*dxl1 + dyl0*dyl0 + dyl1*dyl1 + EPS_S);
    float dxu0 = UR0 - U0, dxu1 = UR1 - U1;
    float dyu0 = C0 - U0, dyu1 = C1 - U1;
    float invSu = rsq_f(dxu0*dxu0 + dxu1*dxu1 + dyu0*dyu0 + dyu1*dyu1 + EPS_S);
    float g0 = -(dxc0 + dyc0) * invSc;
    g0 += dxl0 * invSL;
    g0 += dyu0 * invSu;
    float g1 = -(dxc1 + dyc1) * invSc;
    g1 += dxl1 * invSL;
    g1 += dyu1 * invSu;
    float x0 = upd(C0, g0 * s1v);
    float x1 = upd(C1, g1 * s1v);
    int off = gh * 512 + gw;
    if (!FINAL) {
      unsigned nidx = (unsigned)(b * CHW + off);
      Y[b * 2 * HW + off]      = clip1(x0 + noise_at(kB0, kB1, nidx));
      Y[b * 2 * HW + HW + off] = clip1(x1 + noise_at(kB0, kB1, nidx + (unsigned)HW));
    } else {
      float* outF = Y + OUT_FLOW_OFF + b * 2 * HW;
      outF[off]      = x0 * 80.0f;
      outF[HW + off] = x1 * 80.0f;
    }
  }
}

// img channels: per-pixel independent 200-step recurrence, state in registers.
// Keys prefetched one iteration ahead to hide the LDS read latency.
__global__ __launch_bounds__(256, 8) void k_img(const float* __restrict__ init,
    const float* __restrict__ in2, const float* __restrict__ sw,
    float* __restrict__ out) {
  __shared__ unsigned Kl[404];
  int tid = threadIdx.x;
  if (tid < 202) {                            // split(key(1),200): tf(0,1,0,t); 2 pad
    unsigned a, bb;
    tf2x32(0u, 1u, 0u, (unsigned)tid, a, bb);
    Kl[2 * tid] = a; Kl[2 * tid + 1] = bb;
  }
  __syncthreads();
  int g = blockIdx.x * 256 + tid;             // [0, 8*HW)
  int b = g / HW;
  int p = g - b * HW;
  float s0 = sw[0];
  unsigned base = (unsigned)(b * CHW + 2 * HW + p);   // channel-2 noise index
  float x0 = init[base], x1 = init[base + HW], x2 = init[base + 2 * HW];
  const float* I2 = in2 + b * 3 * HW + p;
  float i0 = ((I2[0] * 2.0f - 1.0f) + 1.0f) * 0.5f;
  float i1 = ((I2[HW] * 2.0f - 1.0f) + 1.0f) * 0.5f;
  float i2v = ((I2[2 * HW] * 2.0f - 1.0f) + 1.0f) * 0.5f;

  unsigned ka = Kl[0], kb = Kl[1];
  for (int t = 0; t < 200; ++t) {
    unsigned kan = Kl[2 * t + 2], kbn = Kl[2 * t + 3];  // prefetch (pad-safe)
    x0 = clip1(x0 + noise_at(ka, kb, base));
    x1 = clip1(x1 + noise_at(ka, kb, base + HW));
    x2 = clip1(x2 + noise_at(ka, kb, base + 2 * HW));
    float d0 = (x0 + 1.0f) * 0.5f - i0;
    float d1 = (x1 + 1.0f) * 0.5f - i1;
    float d2 = (x2 + 1.0f) * 0.5f - i2v;
    float A = d0*d0 + d1*d1 + d2*d2;
    float sI = s0 * rsq_f(A + EPS_F);
    x0 = upd(x0, d0 * sI);
    x1 = upd(x1, d1 * sI);
    x2 = upd(x2, d2 * sI);
    ka = kan; kb = kbn;
  }
  float* outI = out + OUT_IMG_OFF + b * 3 * HW + p;
  outI[0]      = (x0 + 1.0f) * 0.5f;
  outI[HW]     = (x1 + 1.0f) * 0.5f;
  outI[2 * HW] = (x2 + 1.0f) * 0.5f;
}

__device__ __forceinline__ void block_acc2(double v0, double v1, double* a0, double* a1) {
  for (int off = 32; off > 0; off >>= 1) {
    v0 += __shfl_down(v0, off, 64);
    v1 += __shfl_down(v1, off, 64);
  }
  __shared__ double s0m[4], s1m[4];
  int lane = threadIdx.x & 63, wv = threadIdx.x >> 6;
  if (lane == 0) { s0m[wv] = v0; s1m[wv] = v1; }
  __syncthreads();
  if (threadIdx.x == 0) {
    atomicAdd(a0, s0m[0] + s0m[1] + s0m[2] + s0m[3]);
    atomicAdd(a1, s1m[0] + s1m[1] + s1m[2] + s1m[3]);
  }
}

// 96 blocks per batch, each covering 8 contiguous 256-px chunks
__global__ __launch_bounds__(256) void k_pos_energy(const float* __restrict__ t1,
    const float* __restrict__ in1, const float* __restrict__ in2,
    double* __restrict__ acc) {
  int blk = blockIdx.x;
  int b = blk / 96;
  int local = blk - b * 96;
  const float* T0 = t1 + b * 2 * HW;
  const float* T1 = T0 + HW;
  const float* I1 = in1 + b * 3 * HW;
  const float* I2 = in2 + b * 3 * HW;
  double data = 0.0, smooth = 0.0;
  for (int it = 0; it < 8; ++it) {
    int p = (local * 8 + it) * 256 + threadIdx.x;
    int h = p >> 9, w = p & 511;
    float f00 = (T0[p] / 80.0f) * 80.0f;     // mirror (t/80)*80 roundtrip
    float f10 = (T1[p] / 80.0f) * 80.0f;
    float dx0 = 0, dx1 = 0, dy0 = 0, dy1 = 0;
    if (w < 511) { dx0 = (T0[p+1]/80.0f)*80.0f - f00;  dx1 = (T1[p+1]/80.0f)*80.0f - f10; }
    if (h < 383) { dy0 = (T0[p+WW]/80.0f)*80.0f - f00; dy1 = (T1[p+WW]/80.0f)*80.0f - f10; }
    smooth += (double)sqrtf(dx0*dx0 + dx1*dx1 + dy0*dy0 + dy1*dy1 + EPS_F);
    float d0 = ((I1[p]*2.0f-1.0f)+1.0f)*0.5f        - ((I2[p]*2.0f-1.0f)+1.0f)*0.5f;
    float d1 = ((I1[p+HW]*2.0f-1.0f)+1.0f)*0.5f     - ((I2[p+HW]*2.0f-1.0f)+1.0f)*0.5f;
    float d2 = ((I1[p+2*HW]*2.0f-1.0f)+1.0f)*0.5f   - ((I2[p+2*HW]*2.0f-1.0f)+1.0f)*0.5f;
    data += (double)sqrtf(d0*d0 + d1*d1 + d2*d2 + EPS_F);
  }
  block_acc2(data, smooth, &acc[b], &acc[8 + b]);
}

__global__ __launch_bounds__(256) void k_neg_energy(const float* __restrict__ out,
    const float* __restrict__ in2, double* __restrict__ acc) {
  int blk = blockIdx.x;
  int b = blk / 96;
  int local = blk - b * 96;
  const float* F0 = out + OUT_FLOW_OFF + b * 2 * HW;   // already = 80*x
  const float* F1 = F0 + HW;
  const float* I = out + OUT_IMG_OFF + b * 3 * HW;     // already = (x+1)/2
  const float* I2 = in2 + b * 3 * HW;
  double data = 0.0, smooth = 0.0;
  for (int it = 0; it < 8; ++it) {
    int p = (local * 8 + it) * 256 + threadIdx.x;
    int h = p >> 9, w = p & 511;
    float f00 = F0[p], f10 = F1[p];
    float dx0 = 0, dx1 = 0, dy0 = 0, dy1 = 0;
    if (w < 511) { dx0 = F0[p + 1] - f00;  dx1 = F1[p + 1] - f10; }
    if (h < 383) { dy0 = F0[p + WW] - f00; dy1 = F1[p + WW] - f10; }
    smooth += (double)sqrtf(dx0*dx0 + dx1*dx1 + dy0*dy0 + dy1*dy1 + EPS_F);
    float d0 = I[p]        - ((I2[p]*2.0f-1.0f)+1.0f)*0.5f;
    float d1 = I[p+HW]     - ((I2[p+HW]*2.0f-1.0f)+1.0f)*0.5f;
    float d2 = I[p+2*HW]   - ((I2[p+2*HW]*2.0f-1.0f)+1.0f)*0.5f;
    data += (double)sqrtf(d0*d0 + d1*d1 + d2*d2 + EPS_F);
  }
  block_acc2(data, smooth, &acc[16 + b], &acc[24 + b]);
}

__global__ void k_finalize(const double* __restrict__ acc,
                           const float* __restrict__ lw, float* __restrict__ out) {
  int t = threadIdx.x;
  if (t < 16) {
    int b = t & 7, neg = t >> 3;
    double data   = acc[neg * 16 + b];
    double smooth = acc[neg * 16 + 8 + b];
    double e0 = exp((double)lw[0]), e1 = exp((double)lw[1]);
    out[t] = (float)((e0 * data + e1 * smooth) / 196608.0);
  }
}

extern "C" void kernel_launch(void* const* d_in, const int* in_sizes, int n_in,
                              void* d_out, int out_size, void* d_ws, size_t ws_size,
                              hipStream_t stream) {
  const float* t1  = (const float*)d_in[0];
  const float* in1 = (const float*)d_in[1];
  const float* in2 = (const float*)d_in[2];
  const float* init = (const float*)d_in[3];
  const float* lw  = (const float*)d_in[4];
  float* out = (float*)d_out;

  double* acc = (double*)d_ws;                          // 32 doubles
  float* sw = (float*)((char*)d_ws + 256);              // 2 floats
  float* bufFA = (float*)((char*)d_ws + 2048);          // flow ping (12.6 MB)
  size_t need = 2048 + 2 * (size_t)FLOW_N * sizeof(float);
  float* bufFB = (ws_size >= need) ? bufFA + FLOW_N
                                   : out + OUT_FLOW_OFF;  // fallback: d_out flow region

  // host-side threefry split: keys[t] = tf(0,1,0,t)  (pure integer function)
  unsigned K0[200], K1[200];
  for (int t = 0; t < 200; ++t) tf2x32(0u, 1u, 0u, (unsigned)t, K0[t], K1[t]);

  k_init<<<1, 64, 0, stream>>>(acc, sw, lw);
  k_pos_energy<<<8 * 96, 256, 0, stream>>>(t1, in1, in2, acc);

  // ---- flow trajectory: noise_0, then 100 double-steps (T=2 temporal blocking).
  //      Double j: gradA(+noise K[2j+1]), gradB(+noise K[2j+2]); j=99: gradB final.
  k_fnoise0<<<FLOW_N / 256, 256, 0, stream>>>(init, bufFB, K0[0], K1[0]);
  for (int j = 0; j < 99; ++j) {
    const float* src = (j % 2 == 0) ? bufFB : bufFA;
    float* dst       = (j % 2 == 0) ? bufFA : bufFB;
    k_f2<false><<<1536, 256, 0, stream>>>(src, dst, sw,
                                          K0[2*j+1], K1[2*j+1],
                                          K0[2*j+2], K1[2*j+2]);
  }
  k_f2<true><<<1536, 256, 0, stream>>>(bufFA, out, sw, K0[199], K1[199], 0u, 0u);

  // ---- img trajectory: one persistent kernel, all 200 steps in registers
  k_img<<<8 * HW / 256, 256, 0, stream>>>(init, in2, sw, out);

  k_neg_energy<<<8 * 96, 256, 0, stream>>>(out, in2, acc);
  k_finalize<<<1, 64, 0, stream>>>(acc, lw, out);
}

// Round 7
// 5150.237 us; speedup vs baseline: 1.9900x; 1.0222x over previous
//
#include <hip/hip_runtime.h>
#include <math.h>

#define HH 384
#define WW 512
#define HW 196608            // 384*512
#define QHW 49152            // HW/4
#define CHW 983040           // 5*HW
#define NTOT 7864320         // 8*CHW
#define FLOW_N 3145728       // 8*2*HW
#define OUT_FLOW_OFF 16
#define OUT_IMG_OFF (16 + FLOW_N)
#define EPS_F 1e-5f
#define EPS_S (1e-5f / 6400.0f)   // smooth-term eps in raw-x domain (S is deg-1 homog in 80x)
#define INV_HW (1.0f/196608.0f)

// single-instruction HW ops (~1 ulp); med3 == min(max(x,lo),hi) for finite x
__device__ __forceinline__ float rsq_f(float x)  { return __builtin_amdgcn_rsqf(x); }
__device__ __forceinline__ float ln_f(float x)   { return 0.69314718055994531f * __builtin_amdgcn_logf(x); }
__device__ __forceinline__ float sqrt_f(float x) { return __builtin_amdgcn_sqrtf(x); }
__device__ __forceinline__ float med3(float x, float lo, float hi) {
  return __builtin_amdgcn_fmed3f(x, lo, hi);
}

// ---- JAX threefry2x32 (bit-exact integer path), host+device ----
__host__ __device__ __forceinline__ void tf2x32(unsigned k0, unsigned k1,
                                                unsigned x0, unsigned x1,
                                                unsigned& o0, unsigned& o1) {
  const unsigned ks2 = k0 ^ k1 ^ 0x1BD11BDAu;
  x0 += k0; x1 += k1;
#define TFR(r) x0 += x1; x1 = (x1 << (r)) | (x1 >> (32 - (r))); x1 ^= x0;
  TFR(13) TFR(15) TFR(26) TFR(6)
  x0 += k1;  x1 += ks2 + 1u;
  TFR(17) TFR(29) TFR(16) TFR(24)
  x0 += ks2; x1 += k0 + 2u;
  TFR(13) TFR(15) TFR(26) TFR(6)
  x0 += k0;  x1 += k1 + 3u;
  TFR(17) TFR(29) TFR(16) TFR(24)
  x0 += k1;  x1 += ks2 + 4u;
  TFR(13) TFR(15) TFR(26) TFR(6)
  x0 += ks2; x1 += k0 + 5u;
#undef TFR
  o0 = x0; o1 = x1;
}

// bits -> NOISE_STD * sqrt(2) * erfinv(uniform(lo,1))   (JAX normal * 0.05)
__device__ __forceinline__ float noise_from_bits(unsigned bits) {
  const float LO = -0.99999994f;                    // nextafter(-1,0)
  float f = __uint_as_float((bits >> 9) | 0x3F800000u) - 1.0f;  // [0,1)
  float u = fmaxf(LO, f * 2.0f + LO);               // (hi-lo) rounds to 2.0f
  // -log1p(-u^2) via factored form (accurate near |u|~1) + HW log
  float w = -ln_f((1.0f - u) * (1.0f + u));
  float p;
  if (w < 5.0f) {
    w -= 2.5f;
    p = 2.81022636e-08f;
    p = p * w + 3.43273939e-07f;
    p = p * w + -3.5233877e-06f;
    p = p * w + -4.39150654e-06f;
    p = p * w + 0.00021858087f;
    p = p * w + -0.00125372503f;
    p = p * w + -0.00417768164f;
    p = p * w + 0.246640727f;
    p = p * w + 1.50140941f;
  } else {
    w = sqrt_f(w) - 3.0f;
    p = -0.000200214257f;
    p = p * w + 0.000100950558f;
    p = p * w + 0.00134934322f;
    p = p * w + -0.00367342844f;
    p = p * w + 0.00573950773f;
    p = p * w + -0.0076224613f;
    p = p * w + 0.00943887047f;
    p = p * w + 1.00167406f;
    p = p * w + 2.83297682f;
  }
  float z = 1.4142135623730951f * (p * u);
  return 0.05f * z;
}

__device__ __forceinline__ float upd(float x, float g) {
  g = med3(g, -0.03f, 0.03f);
  return med3(x - 10.0f * g, -1.0f, 1.0f);
}

__device__ __forceinline__ float noise_at(unsigned ka, unsigned kb, unsigned idx) {
  unsigned o0, o1;
  tf2x32(ka, kb, 0u, idx, o0, o1);
  return noise_from_bits(o0 ^ o1);
}

__device__ __forceinline__ float clip1(float x) { return med3(x, -1.0f, 1.0f); }

// add noise to 4 results and store as float4 (non-final path)
__device__ __forceinline__ void noise_store4(float* dst, const float xn[4],
                                             unsigned ka, unsigned kb, unsigned idx0) {
  float r[4];
#pragma unroll
  for (int j = 0; j < 4; ++j)
    r[j] = clip1(xn[j] + noise_at(ka, kb, idx0 + (unsigned)j));
  *(float4*)dst = make_float4(r[0], r[1], r[2], r[3]);
}

// ---- kernels ----
__global__ void k_init(double* acc, float* sw, const float* lw) {
  int t = threadIdx.x;
  if (t < 32) acc[t] = 0.0;
  if (t == 32) {
    sw[0] = expf(lw[0]) * INV_HW * 0.5f;    // data-term scale
    sw[1] = expf(lw[1]) * INV_HW * 80.0f;   // smooth-term scale (incl d(flow)/dx = 80)
  }
}

// flow noise_0: compact (B,2,H,W) buffer, noise indexed in original 5-ch layout
__global__ __launch_bounds__(256) void k_fnoise0(const float* __restrict__ init,
    float* __restrict__ Y, unsigned ka, unsigned kb) {
  int e = blockIdx.x * 256 + threadIdx.x;    // [0, FLOW_N)
  int b = e / (2 * HW);
  int r = e - b * 2 * HW;
  int orig = b * CHW + r;                    // original element index (channels 0..1)
  Y[e] = clip1(init[orig] + noise_at(ka, kb, (unsigned)orig));
}

// flow grad step, 4 px/thread along w -> 1536 blocks = 24 waves/CU, ONE residency
// round (no tail). State compact (B,2,H,W), raw-x domain (80 folded into s1/EPS_S).
template <bool FINAL>
__global__ __launch_bounds__(256) void k_fstep4(const float* __restrict__ X,
    float* __restrict__ Y, const float* __restrict__ sw,
    unsigned ka, unsigned kb) {
  int tid = blockIdx.x * 256 + threadIdx.x;   // [0, 8*QHW)
  int b = tid / QHW;
  int q = tid - b * QHW;
  int p = q * 4;                              // pixel base, multiple of 4
  int h = p >> 9, w = p & 511;
  float s1v = sw[1];
  const float* F0 = X + b * 2 * HW;
  const float* F1 = F0 + HW;
  const bool wpos = (w > 0), wend = (w == 508);
  const bool hpos = (h > 0), hlast = (h == 383);

  // ---- stencil values; cf[c][4] duplicated at right edge so dx=0 ----
  float cf[2][5], fm1[2], dw[2][4], dwm1[2], uf[2][5];
  {
    float4 a0 = *(const float4*)(F0 + p);
    float4 a1 = *(const float4*)(F1 + p);
    cf[0][0]=a0.x; cf[0][1]=a0.y; cf[0][2]=a0.z; cf[0][3]=a0.w;
    cf[1][0]=a1.x; cf[1][1]=a1.y; cf[1][2]=a1.z; cf[1][3]=a1.w;
    cf[0][4] = wend ? cf[0][3] : F0[p + 4];
    cf[1][4] = wend ? cf[1][3] : F1[p + 4];
    fm1[0] = wpos ? F0[p - 1] : cf[0][0];
    fm1[1] = wpos ? F1[p - 1] : cf[1][0];
    if (!hlast) {
      float4 d0 = *(const float4*)(F0 + p + WW);
      float4 d1 = *(const float4*)(F1 + p + WW);
      dw[0][0]=d0.x; dw[0][1]=d0.y; dw[0][2]=d0.z; dw[0][3]=d0.w;
      dw[1][0]=d1.x; dw[1][1]=d1.y; dw[1][2]=d1.z; dw[1][3]=d1.w;
      dwm1[0] = wpos ? F0[p + WW - 1] : fm1[0];
      dwm1[1] = wpos ? F1[p + WW - 1] : fm1[1];
    } else {
#pragma unroll
      for (int c = 0; c < 2; ++c) {
        for (int j = 0; j < 4; ++j) dw[c][j] = cf[c][j];   // dy = 0
        dwm1[c] = fm1[c];
      }
    }
    if (hpos) {
      float4 u0 = *(const float4*)(F0 + p - WW);
      float4 u1 = *(const float4*)(F1 + p - WW);
      uf[0][0]=u0.x; uf[0][1]=u0.y; uf[0][2]=u0.z; uf[0][3]=u0.w;
      uf[1][0]=u1.x; uf[1][1]=u1.y; uf[1][2]=u1.z; uf[1][3]=u1.w;
      uf[0][4] = wend ? uf[0][3] : F0[p - WW + 4];
      uf[1][4] = wend ? uf[1][3] : F1[p - WW + 4];
    } else {
#pragma unroll
      for (int c = 0; c < 2; ++c)
        for (int j = 0; j < 5; ++j) uf[c][j] = cf[c][j];   // unused (masked by hpos)
    }
  }

  // ---- shared S sites: SL = S(h,w-1); Sc[j] = S(h,w+j); Su[j] = S(h-1,w+j) ----
  float dxc[2][4], dyc[2][4], invSc[4], dxu[2][4], dyu[2][4], invSu[4];
  float dxl[2], dyl[2], invSL;
#pragma unroll
  for (int j = 0; j < 4; ++j) {
#pragma unroll
    for (int c = 0; c < 2; ++c) {
      dxc[c][j] = cf[c][j + 1] - cf[c][j];
      dyc[c][j] = dw[c][j] - cf[c][j];
      dxu[c][j] = uf[c][j + 1] - uf[c][j];
      dyu[c][j] = cf[c][j] - uf[c][j];
    }
    invSc[j] = rsq_f(dxc[0][j]*dxc[0][j] + dxc[1][j]*dxc[1][j]
                   + dyc[0][j]*dyc[0][j] + dyc[1][j]*dyc[1][j] + EPS_S);
    invSu[j] = rsq_f(dxu[0][j]*dxu[0][j] + dxu[1][j]*dxu[1][j]
                   + dyu[0][j]*dyu[0][j] + dyu[1][j]*dyu[1][j] + EPS_S);
  }
  dxl[0] = cf[0][0] - fm1[0];  dxl[1] = cf[1][0] - fm1[1];
  dyl[0] = dwm1[0] - fm1[0];   dyl[1] = dwm1[1] - fm1[1];
  invSL = rsq_f(dxl[0]*dxl[0] + dxl[1]*dxl[1]
              + dyl[0]*dyl[0] + dyl[1]*dyl[1] + EPS_S);

  // ---- grads + update ----
  float xnF[2][4];
#pragma unroll
  for (int j = 0; j < 4; ++j) {
#pragma unroll
    for (int c = 0; c < 2; ++c) {
      float g = -(dxc[c][j] + dyc[c][j]) * invSc[j];
      if (j == 0) { if (wpos) g += dxl[c] * invSL; }
      else        { g += dxc[c][j - 1] * invSc[j - 1]; }
      if (hpos)   { g += dyu[c][j] * invSu[j]; }
      xnF[c][j] = upd(cf[c][j], g * s1v);
    }
  }

  // ---- noise + store (or final transform) ----
  if (!FINAL) {
    int nbase = b * CHW + p;                 // noise index in original 5-ch layout
    int sb = b * 2 * HW + p;                 // compact store index
    noise_store4(Y + sb,      xnF[0], ka, kb, (unsigned)nbase);
    noise_store4(Y + sb + HW, xnF[1], ka, kb, (unsigned)(nbase + HW));
  } else {
    float* outF = Y + OUT_FLOW_OFF + b * 2 * HW;
    *(float4*)(outF + p)      = make_float4(xnF[0][0]*80.f, xnF[0][1]*80.f,
                                            xnF[0][2]*80.f, xnF[0][3]*80.f);
    *(float4*)(outF + HW + p) = make_float4(xnF[1][0]*80.f, xnF[1][1]*80.f,
                                            xnF[1][2]*80.f, xnF[1][3]*80.f);
  }
}

// img channels: per-pixel independent 200-step recurrence, state in registers.
// Keys prefetched one iteration ahead to hide the LDS read latency.
__global__ __launch_bounds__(256, 8) void k_img(const float* __restrict__ init,
    const float* __restrict__ in2, const float* __restrict__ sw,
    float* __restrict__ out) {
  __shared__ unsigned Kl[404];
  int tid = threadIdx.x;
  if (tid < 202) {                            // split(key(1),200): tf(0,1,0,t); 2 pad
    unsigned a, bb;
    tf2x32(0u, 1u, 0u, (unsigned)tid, a, bb);
    Kl[2 * tid] = a; Kl[2 * tid + 1] = bb;
  }
  __syncthreads();
  int g = blockIdx.x * 256 + tid;             // [0, 8*HW)
  int b = g / HW;
  int p = g - b * HW;
  float s0 = sw[0];
  unsigned base = (unsigned)(b * CHW + 2 * HW + p);   // channel-2 noise index
  float x0 = init[base], x1 = init[base + HW], x2 = init[base + 2 * HW];
  const float* I2 = in2 + b * 3 * HW + p;
  float i0 = ((I2[0] * 2.0f - 1.0f) + 1.0f) * 0.5f;
  float i1 = ((I2[HW] * 2.0f - 1.0f) + 1.0f) * 0.5f;
  float i2v = ((I2[2 * HW] * 2.0f - 1.0f) + 1.0f) * 0.5f;

  unsigned ka = Kl[0], kb = Kl[1];
  for (int t = 0; t < 200; ++t) {
    unsigned kan = Kl[2 * t + 2], kbn = Kl[2 * t + 3];  // prefetch (pad-safe)
    x0 = clip1(x0 + noise_at(ka, kb, base));
    x1 = clip1(x1 + noise_at(ka, kb, base + HW));
    x2 = clip1(x2 + noise_at(ka, kb, base + 2 * HW));
    float d0 = (x0 + 1.0f) * 0.5f - i0;
    float d1 = (x1 + 1.0f) * 0.5f - i1;
    float d2 = (x2 + 1.0f) * 0.5f - i2v;
    float A = d0*d0 + d1*d1 + d2*d2;
    float sI = s0 * rsq_f(A + EPS_F);
    x0 = upd(x0, d0 * sI);
    x1 = upd(x1, d1 * sI);
    x2 = upd(x2, d2 * sI);
    ka = kan; kb = kbn;
  }
  float* outI = out + OUT_IMG_OFF + b * 3 * HW + p;
  outI[0]      = (x0 + 1.0f) * 0.5f;
  outI[HW]     = (x1 + 1.0f) * 0.5f;
  outI[2 * HW] = (x2 + 1.0f) * 0.5f;
}

__device__ __forceinline__ void block_acc2(double v0, double v1, double* a0, double* a1) {
  for (int off = 32; off > 0; off >>= 1) {
    v0 += __shfl_down(v0, off, 64);
    v1 += __shfl_down(v1, off, 64);
  }
  __shared__ double s0m[4], s1m[4];
  int lane = threadIdx.x & 63, wv = threadIdx.x >> 6;
  if (lane == 0) { s0m[wv] = v0; s1m[wv] = v1; }
  __syncthreads();
  if (threadIdx.x == 0) {
    atomicAdd(a0, s0m[0] + s0m[1] + s0m[2] + s0m[3]);
    atomicAdd(a1, s1m[0] + s1m[1] + s1m[2] + s1m[3]);
  }
}

// 96 blocks per batch, each covering 8 contiguous 256-px chunks
__global__ __launch_bounds__(256) void k_pos_energy(const float* __restrict__ t1,
    const float* __restrict__ in1, const float* __restrict__ in2,
    double* __restrict__ acc) {
  int blk = blockIdx.x;
  int b = blk / 96;
  int local = blk - b * 96;
  const float* T0 = t1 + b * 2 * HW;
  const float* T1 = T0 + HW;
  const float* I1 = in1 + b * 3 * HW;
  const float* I2 = in2 + b * 3 * HW;
  double data = 0.0, smooth = 0.0;
  for (int it = 0; it < 8; ++it) {
    int p = (local * 8 + it) * 256 + threadIdx.x;
    int h = p >> 9, w = p & 511;
    float f00 = (T0[p] / 80.0f) * 80.0f;     // mirror (t/80)*80 roundtrip
    float f10 = (T1[p] / 80.0f) * 80.0f;
    float dx0 = 0, dx1 = 0, dy0 = 0, dy1 = 0;
    if (w < 511) { dx0 = (T0[p+1]/80.0f)*80.0f - f00;  dx1 = (T1[p+1]/80.0f)*80.0f - f10; }
    if (h < 383) { dy0 = (T0[p+WW]/80.0f)*80.0f - f00; dy1 = (T1[p+WW]/80.0f)*80.0f - f10; }
    smooth += (double)sqrtf(dx0*dx0 + dx1*dx1 + dy0*dy0 + dy1*dy1 + EPS_F);
    float d0 = ((I1[p]*2.0f-1.0f)+1.0f)*0.5f        - ((I2[p]*2.0f-1.0f)+1.0f)*0.5f;
    float d1 = ((I1[p+HW]*2.0f-1.0f)+1.0f)*0.5f     - ((I2[p+HW]*2.0f-1.0f)+1.0f)*0.5f;
    float d2 = ((I1[p+2*HW]*2.0f-1.0f)+1.0f)*0.5f   - ((I2[p+2*HW]*2.0f-1.0f)+1.0f)*0.5f;
    data += (double)sqrtf(d0*d0 + d1*d1 + d2*d2 + EPS_F);
  }
  block_acc2(data, smooth, &acc[b], &acc[8 + b]);
}

__global__ __launch_bounds__(256) void k_neg_energy(const float* __restrict__ out,
    const float* __restrict__ in2, double* __restrict__ acc) {
  int blk = blockIdx.x;
  int b = blk / 96;
  int local = blk - b * 96;
  const float* F0 = out + OUT_FLOW_OFF + b * 2 * HW;   // already = 80*x
  const float* F1 = F0 + HW;
  const float* I = out + OUT_IMG_OFF + b * 3 * HW;     // already = (x+1)/2
  const float* I2 = in2 + b * 3 * HW;
  double data = 0.0, smooth = 0.0;
  for (int it = 0; it < 8; ++it) {
    int p = (local * 8 + it) * 256 + threadIdx.x;
    int h = p >> 9, w = p & 511;
    float f00 = F0[p], f10 = F1[p];
    float dx0 = 0, dx1 = 0, dy0 = 0, dy1 = 0;
    if (w < 511) { dx0 = F0[p + 1] - f00;  dx1 = F1[p + 1] - f10; }
    if (h < 383) { dy0 = F0[p + WW] - f00; dy1 = F1[p + WW] - f10; }
    smooth += (double)sqrtf(dx0*dx0 + dx1*dx1 + dy0*dy0 + dy1*dy1 + EPS_F);
    float d0 = I[p]        - ((I2[p]*2.0f-1.0f)+1.0f)*0.5f;
    float d1 = I[p+HW]     - ((I2[p+HW]*2.0f-1.0f)+1.0f)*0.5f;
    float d2 = I[p+2*HW]   - ((I2[p+2*HW]*2.0f-1.0f)+1.0f)*0.5f;
    data += (double)sqrtf(d0*d0 + d1*d1 + d2*d2 + EPS_F);
  }
  block_acc2(data, smooth, &acc[16 + b], &acc[24 + b]);
}

__global__ void k_finalize(const double* __restrict__ acc,
                           const float* __restrict__ lw, float* __restrict__ out) {
  int t = threadIdx.x;
  if (t < 16) {
    int b = t & 7, neg = t >> 3;
    double data   = acc[neg * 16 + b];
    double smooth = acc[neg * 16 + 8 + b];
    double e0 = exp((double)lw[0]), e1 = exp((double)lw[1]);
    out[t] = (float)((e0 * data + e1 * smooth) / 196608.0);
  }
}

extern "C" void kernel_launch(void* const* d_in, const int* in_sizes, int n_in,
                              void* d_out, int out_size, void* d_ws, size_t ws_size,
                              hipStream_t stream) {
  const float* t1  = (const float*)d_in[0];
  const float* in1 = (const float*)d_in[1];
  const float* in2 = (const float*)d_in[2];
  const float* init = (const float*)d_in[3];
  const float* lw  = (const float*)d_in[4];
  float* out = (float*)d_out;

  double* acc = (double*)d_ws;                          // 32 doubles
  float* sw = (float*)((char*)d_ws + 256);              // 2 floats
  float* bufFA = (float*)((char*)d_ws + 2048);          // flow ping (12.6 MB)
  size_t need = 2048 + 2 * (size_t)FLOW_N * sizeof(float);
  float* bufFB = (ws_size >= need) ? bufFA + FLOW_N
                                   : out + OUT_FLOW_OFF;  // fallback: d_out flow region

  // host-side threefry split: keys[t] = tf(0,1,0,t)  (pure integer function)
  unsigned K0[200], K1[200];
  for (int t = 0; t < 200; ++t) tf2x32(0u, 1u, 0u, (unsigned)t, K0[t], K1[t]);

  k_init<<<1, 64, 0, stream>>>(acc, sw, lw);
  k_pos_energy<<<8 * 96, 256, 0, stream>>>(t1, in1, in2, acc);

  // ---- flow trajectory: noise_0, then 199 grad(+noise) steps, then final grad.
  //      Parity: noise0 -> bufFB; t even FB->FA, t odd FA->FB; t=198 even -> FA;
  //      FINAL reads bufFA (never aliases out).
  k_fnoise0<<<FLOW_N / 256, 256, 0, stream>>>(init, bufFB, K0[0], K1[0]);
  for (int t = 0; t < 199; ++t) {
    const float* src = (t % 2 == 0) ? bufFB : bufFA;
    float* dst       = (t % 2 == 0) ? bufFA : bufFB;
    k_fstep4<false><<<8 * QHW / 256, 256, 0, stream>>>(src, dst, sw,
                                                       K0[t + 1], K1[t + 1]);
  }
  k_fstep4<true><<<8 * QHW / 256, 256, 0, stream>>>(bufFA, out, sw, 0u, 0u);

  // ---- img trajectory: one persistent kernel, all 200 steps in registers
  k_img<<<8 * HW / 256, 256, 0, stream>>>(init, in2, sw, out);

  k_neg_energy<<<8 * 96, 256, 0, stream>>>(out, in2, acc);
  k_finalize<<<1, 64, 0, stream>>>(acc, lw, out);
}